// Round 6
// baseline (261.524 us; speedup 1.0000x reference)
//
#include <hip/hip_runtime.h>
#include <hip/hip_bf16.h>

#define NTOK 2048
#define DIM  1024
#define DEXP 512
#define NEXP 8
#define DSH  1024          // shared expert width
#define KH   5120          // DSH + NEXP*DEXP (packed Bg/Bu row count; Bd col count)
#define MAXROWS 5120       // compacted routed slots upper bound
#define PACKBLOCKS 3840    // 15.75M weight elems / 4096 per 64x64 tile

typedef __hip_bfloat16 bf16;
typedef __attribute__((ext_vector_type(8))) short bf16x8;
typedef __attribute__((ext_vector_type(4))) float floatx4;

// async global->LDS, 16B/lane. LDS dest = wave-uniform base + lane*16 (HW adds).
__device__ __forceinline__ void gl_lds16(const bf16* g, bf16* l) {
    __builtin_amdgcn_global_load_lds(
        (const __attribute__((address_space(1))) void*)g,
        (__attribute__((address_space(3))) void*)l, 16, 0, 0);
}

struct B4 { bf16 a, b, c, d; };   // 8-byte bf16 quad

// ---------------------------------------------------------------------------
// Fused weight-pack + gating kernel (128 threads/block).
// ---------------------------------------------------------------------------
__global__ __launch_bounds__(128) void pack_gate(
        const float* __restrict__ Wg_s, const float* __restrict__ Wu_s,
        const float* __restrict__ Wg_e, const float* __restrict__ Wu_e,
        const float* __restrict__ Wd_s, const float* __restrict__ Wd_e,
        const float* __restrict__ x, const float* __restrict__ Wg,
        bf16* __restrict__ Bg, bf16* __restrict__ Bu, bf16* __restrict__ Bd,
        bf16* __restrict__ Xb, int2* __restrict__ te, float2* __restrict__ tp) {
    int b = blockIdx.x;
    const int tid = threadIdx.x;
    if (b < PACKBLOCKS) {
        // ---- pack: src [R][C] fp32, dst[h = src col][k = src row] bf16 ----
        __shared__ unsigned lt[64][35];
        const float* src; bf16* dst; int C; long dstStride, dstBase; int tilesX;
        if (b < 256)        { src = Wg_s; dst = Bg; C = 1024; dstStride = 1024; dstBase = 0; tilesX = 16; }
        else if (b < 1280)  { int z = (b - 256) >> 7; b = (b - 256) & 127;
                              src = Wg_e + (long)z * DIM * DEXP; dst = Bg; C = 512;
                              dstStride = 1024; dstBase = (long)(DSH + z * DEXP) * 1024; tilesX = 8; }
        else if (b < 1536)  { b -= 1280; src = Wu_s; dst = Bu; C = 1024; dstStride = 1024; dstBase = 0; tilesX = 16; }
        else if (b < 2560)  { int z = (b - 1536) >> 7; b = (b - 1536) & 127;
                              src = Wu_e + (long)z * DIM * DEXP; dst = Bu; C = 512;
                              dstStride = 1024; dstBase = (long)(DSH + z * DEXP) * 1024; tilesX = 8; }
        else if (b < 2816)  { b -= 2560; src = Wd_s; dst = Bd; C = 1024; dstStride = KH; dstBase = 0; tilesX = 16; }
        else                { int z = (b - 2816) >> 7; b = (b - 2816) & 127;
                              src = Wd_e + (long)z * DEXP * DIM; dst = Bd; C = 1024;
                              dstStride = KH; dstBase = DSH + (long)z * DEXP; tilesX = 16; }
        const int tileX = b & (tilesX - 1), tileY = b / tilesX;
        const int c0 = tileX * 64, r0 = tileY * 64;

        // load 64x64 fp32, 8 independent float4/lane, cvt->bf16, pack to LDS
        const int lrow = tid >> 4, lch = tid & 15;
#pragma unroll
        for (int i = 0; i < 8; i++) {
            int row = lrow + i * 8;
            float4 v = *(const float4*)(src + (long)(r0 + row) * C + c0 + lch * 4);
            union { bf16 h[2]; unsigned u; } p0, p1;
            p0.h[0] = __float2bfloat16(v.x); p0.h[1] = __float2bfloat16(v.y);
            p1.h[0] = __float2bfloat16(v.z); p1.h[1] = __float2bfloat16(v.w);
            lt[row][lch * 2]     = p0.u;
            lt[row][lch * 2 + 1] = p1.u;
        }
        __syncthreads();
        // transposed store: each lane emits one 16B bf16x8 (8 k of one h)
        const int kc = tid & 7;
#pragma unroll
        for (int i = 0; i < 4; i++) {
            int h = (tid >> 3) + i * 16;
            union { unsigned short s[8]; bf16x8 v8; } o;
#pragma unroll
            for (int j = 0; j < 8; j++)
                o.s[j] = ((const unsigned short*)lt[kc * 8 + j])[h];
            *(bf16x8*)(dst + dstBase + (long)(c0 + h) * dstStride + r0 + kc * 8) = o.v8;
        }
    } else {
        // ---- gating: one wave/token, fp32 logits -> softmax -> top-2 ----
        int t = (b - PACKBLOCKS) * 2 + (tid >> 6);
        int lane = tid & 63;
        const float* xr = x + (long)t * DIM;
        bf16* xo = Xb + (long)t * DIM;
        float acc[NEXP] = {0.f, 0.f, 0.f, 0.f, 0.f, 0.f, 0.f, 0.f};
#pragma unroll
        for (int i = 0; i < 4; i++) {
            int d = lane * 4 + i * 256;
            float4 xv = *(const float4*)(xr + d);
            B4 o{__float2bfloat16(xv.x), __float2bfloat16(xv.y),
                 __float2bfloat16(xv.z), __float2bfloat16(xv.w)};
            *(B4*)(xo + d) = o;
#pragma unroll
            for (int j = 0; j < 4; j++) {
                float xs = (j == 0) ? xv.x : (j == 1) ? xv.y : (j == 2) ? xv.z : xv.w;
                float4 w0 = *(const float4*)(Wg + (d + j) * NEXP);
                float4 w1 = *(const float4*)(Wg + (d + j) * NEXP + 4);
                acc[0] += xs * w0.x; acc[1] += xs * w0.y; acc[2] += xs * w0.z; acc[3] += xs * w0.w;
                acc[4] += xs * w1.x; acc[5] += xs * w1.y; acc[6] += xs * w1.z; acc[7] += xs * w1.w;
            }
        }
#pragma unroll
        for (int e = 0; e < NEXP; e++)
#pragma unroll
            for (int off = 32; off; off >>= 1)
                acc[e] += __shfl_xor(acc[e], off);
        if (lane == 0) {
            float m = acc[0];
#pragma unroll
            for (int e = 1; e < NEXP; e++) m = fmaxf(m, acc[e]);
            float p[NEXP], s = 0.f;
#pragma unroll
            for (int e = 0; e < NEXP; e++) { p[e] = expf(acc[e] - m); s += p[e]; }
            float inv = 1.f / s;
#pragma unroll
            for (int e = 0; e < NEXP; e++) p[e] *= inv;
            int i1 = 0;
#pragma unroll
            for (int e = 1; e < NEXP; e++) if (p[e] > p[i1]) i1 = e;   // strict >: lowest idx on tie
            int i2 = (i1 == 0) ? 1 : 0;
#pragma unroll
            for (int e = 0; e < NEXP; e++) if (e != i1 && p[e] > p[i2]) i2 = e;
            te[t] = make_int2(i1, i2);
            tp[t] = make_float2(p[i1], p[i2]);
        }
    }
}

// ---------------------------------------------------------------------------
// Phase-2 slot assignment: 1 block, 8 waves; wave e scans all tokens with
// ballot prefix -> deterministic slots. Zero atomics. Also zeroes the pad
// slots (token 0, weight 0) so no separate memset dispatch is needed.
// ---------------------------------------------------------------------------
__global__ __launch_bounds__(512) void assign_kernel(const int2* __restrict__ te,
                                                     const float2* __restrict__ tp,
                                                     int* __restrict__ counts,
                                                     int* __restrict__ offs,
                                                     int* __restrict__ tok_list,
                                                     float* __restrict__ cw) {
    __shared__ int cnt[NEXP];
    const int e = threadIdx.x >> 6;
    const int lane = threadIdx.x & 63;
    int base = 0;
    for (int t0 = 0; t0 < NTOK; t0 += 64) {
        int t = t0 + lane;
        int2 ee = te[t];
        bool m1 = (ee.x == e), m2 = (ee.y == e);
        bool mt = m1 || m2;
        unsigned long long mask = __ballot(mt);
        int pre = __popcll(mask & ((1ull << lane) - 1ull));
        if (mt) {
            int slot = base + pre;
            tok_list[e * NTOK + slot] = t;
            float2 pp = tp[t];
            cw[e * NTOK + slot] = m1 ? pp.x : pp.y;
        }
        base += __popcll(mask);
    }
    // zero pad slots up to the 128-rounded count (read as token 0 / weight 0)
    int rounded = (base + 127) & ~127;
    for (int s = base + lane; s < rounded; s += 64) {
        tok_list[e * NTOK + s] = 0;
        cw[e * NTOK + s] = 0.f;
    }
    if (lane == 0) cnt[e] = base;
    __syncthreads();
    if (threadIdx.x == 0) {
        int o = 0;
#pragma unroll
        for (int i = 0; i < NEXP; i++) {
            counts[i] = cnt[i];
            offs[i] = o;
            o += (cnt[i] + 127) & ~127;
        }
    }
}

// ---------------------------------------------------------------------------
// Unified gate+up SwiGLU GEMM (shared + gathered routed), tile 128x64, BK=32,
// 4 waves 2x2. XOR-swizzled LDS -> 0 conflicts.
// T3+T4: 3 LDS buffers, counted vmcnt, never drains to 0 mid-loop.
// (R3 structure, measured 40.8us; XCD-affine remap of R5 reverted — it
//  regressed by funneling the token-row gather through one XCD.)
// ---------------------------------------------------------------------------
__global__ __launch_bounds__(256) void gu_all(const bf16* __restrict__ X,
                                              const bf16* __restrict__ Bg,
                                              const bf16* __restrict__ Bu,
                                              const int* __restrict__ counts,
                                              const int* __restrict__ offs,
                                              const int* __restrict__ tok_list,
                                              const float* __restrict__ cw,
                                              bf16* __restrict__ Hs,
                                              bf16* __restrict__ He) {
    __shared__ __align__(16) bf16 sA[3][128 * 32];
    __shared__ __align__(16) bf16 sBg[3][64 * 32];
    __shared__ __align__(16) bf16 sBu[3][64 * 32];

    const int b = blockIdx.x;
    const bool routed = b < 1024;
    int e = 0, m, c;
    if (routed) {
        e = b >> 7; m = (b >> 3) & 15; c = b & 7;
        if (m * 128 >= counts[e]) return;
    } else {
        int bs = b - 1024; m = bs >> 4; c = bs & 15;
    }
    const int so = routed ? offs[e] : 0;               // compacted slot base
    const int colB0 = routed ? (DSH + e * DEXP + c * 64) : c * 64;

    const int tid = threadIdx.x;
    const int wave = tid >> 6, lane = tid & 63;
    const int wr = wave >> 1, wc = wave & 1;
    const int q = lane >> 4, l15 = lane & 15;
    const int koff = (q ^ ((l15 >> 1) & 3)) * 8;       // swizzled fragment read

    const int r0 = tid >> 2, c4 = tid & 3;
    const int r1 = r0 + 64;
    const int c4s = c4 ^ ((r0 >> 1) & 3);
    long aRow0, aRow1;
    if (routed) {
        const int* tl = tok_list + e * NTOK + m * 128;
        aRow0 = (long)tl[r0] * DIM;
        aRow1 = (long)tl[r1] * DIM;
    } else {
        aRow0 = (long)(m * 128 + r0) * DIM;
        aRow1 = (long)(m * 128 + r1) * DIM;
    }
    const long bRow = (long)(colB0 + r0) * DIM;

    floatx4 accG[4][2], accU[4][2];
    const floatx4 z4 = {0.f, 0.f, 0.f, 0.f};
#pragma unroll
    for (int i = 0; i < 4; i++)
#pragma unroll
        for (int j = 0; j < 2; j++) { accG[i][j] = z4; accU[i][j] = z4; }

    auto stage = [&](int bb, int k0) {
        gl_lds16(X + aRow0 + k0 + c4s * 8, &sA[bb][wave * 512]);
        gl_lds16(X + aRow1 + k0 + c4s * 8, &sA[bb][2048 + wave * 512]);
        gl_lds16(Bg + bRow + k0 + c4s * 8, &sBg[bb][wave * 512]);
        gl_lds16(Bu + bRow + k0 + c4s * 8, &sBu[bb][wave * 512]);
    };
    auto compute = [&](int bb) {
        bf16x8 af[4], bgv[2], buv[2];
#pragma unroll
        for (int rt = 0; rt < 4; rt++)
            af[rt] = *(const bf16x8*)(&sA[bb][(wr * 64 + rt * 16 + l15) * 32 + koff]);
#pragma unroll
        for (int ct = 0; ct < 2; ct++) {
            int cb = (wc * 32 + ct * 16 + l15) * 32 + koff;
            bgv[ct] = *(const bf16x8*)(&sBg[bb][cb]);
            buv[ct] = *(const bf16x8*)(&sBu[bb][cb]);
        }
#pragma unroll
        for (int rt = 0; rt < 4; rt++)
#pragma unroll
            for (int ct = 0; ct < 2; ct++) {
                accG[rt][ct] = __builtin_amdgcn_mfma_f32_16x16x32_bf16(af[rt], bgv[ct], accG[rt][ct], 0, 0, 0);
                accU[rt][ct] = __builtin_amdgcn_mfma_f32_16x16x32_bf16(af[rt], buv[ct], accU[rt][ct], 0, 0, 0);
            }
    };

    const int NS = DIM / 32;               // 32 K-steps
    stage(0, 0);
    stage(1, 32);                          // 2 stages (8 loads) in flight
    int bb = 0;
    for (int ks = 0; ks < NS; ks++) {
        if (ks + 2 < NS) stage((bb + 2) % 3, (ks + 2) * 32);
        // wait: buffer ks's 4 loads done; stages ks+1,ks+2 stay in flight
        if (ks + 2 < NS)      asm volatile("s_waitcnt vmcnt(8)" ::: "memory");
        else if (ks + 1 < NS) asm volatile("s_waitcnt vmcnt(4)" ::: "memory");
        else                  asm volatile("s_waitcnt vmcnt(0)" ::: "memory");
        __builtin_amdgcn_s_barrier();      // raw: no compiler vmcnt(0) drain
        asm volatile("" ::: "memory");
        compute(bb);
        asm volatile("" ::: "memory");
        __builtin_amdgcn_s_barrier();      // protect buffer bb from next stage
        bb = (bb + 1) % 3;
    }

    // epilogue: silu(g)*u*w  (C/D layout: col=lane&15, row=q*4+reg)
    float wv[4][4];
#pragma unroll
    for (int rt = 0; rt < 4; rt++)
#pragma unroll
        for (int r = 0; r < 4; r++) {
            int srow = wr * 64 + rt * 16 + q * 4 + r;
            wv[rt][r] = routed ? cw[e * NTOK + m * 128 + srow] : 1.0f;
        }
#pragma unroll
    for (int rt = 0; rt < 4; rt++)
#pragma unroll
        for (int ct = 0; ct < 2; ct++)
#pragma unroll
            for (int r = 0; r < 4; r++) {
                int srow = wr * 64 + rt * 16 + q * 4 + r;
                int colLoc = c * 64 + wc * 32 + ct * 16 + l15;
                float g = accG[rt][ct][r];
                float u = accU[rt][ct][r];
                float h = (g / (1.f + __expf(-g))) * u * wv[rt][r];
                if (routed)
                    He[(long)(so + m * 128 + srow) * DEXP + colLoc] = __float2bfloat16(h);
                else
                    Hs[(long)(m * 128 + srow) * DSH + colLoc] = __float2bfloat16(h);
            }
}

// ---------------------------------------------------------------------------
// Unified down GEMM, fused combine: every block atomicAdds its fp32 tile
// directly into out[token][d] (out pre-zeroed). Routed rows map slot->token
// via tok_list; pad slots have He==0 and tok_list==0 -> add 0.0 to token 0.
// Removes the Ys/Ye round-trip (~32MB HBM) and the combine dispatch.
// Same counted-vmcnt 3-buffer pipeline as gu_all.
// ---------------------------------------------------------------------------
__global__ __launch_bounds__(256) void down_all(const bf16* __restrict__ Hs,
                                                const bf16* __restrict__ He,
                                                const bf16* __restrict__ Bd,
                                                const int* __restrict__ counts,
                                                const int* __restrict__ offs,
                                                const int* __restrict__ tok_list,
                                                float* __restrict__ out) {
    __shared__ __align__(16) bf16 sA[3][128 * 32];
    __shared__ __align__(16) bf16 sB[3][64 * 32];

    const int b = blockIdx.x;
    const bool routed = b < 2048;
    int e = 0, m, cc;
    if (routed) {
        e = b >> 8; m = (b >> 4) & 15; cc = b & 15;
        if (m * 128 >= counts[e]) return;
    } else {
        int bs = b - 2048; m = bs >> 4; cc = bs & 15;
    }
    const int so = routed ? offs[e] : 0;
    const bf16* A = routed ? He + (long)so * DEXP : Hs;
    const int astr = routed ? DEXP : DSH;
    const int ksteps = routed ? (DEXP / 32) : (DSH / 32);
    const int kg0 = routed ? (DSH + e * DEXP) : 0;     // K-offset within Bd rows

    const int tid = threadIdx.x;
    const int wave = tid >> 6, lane = tid & 63;
    const int wr = wave >> 1, wc = wave & 1;
    const int q = lane >> 4, l15 = lane & 15;
    const int koff = (q ^ ((l15 >> 1) & 3)) * 8;

    const int r0 = tid >> 2, c4 = tid & 3;
    const int r1 = r0 + 64;
    const int c4s = c4 ^ ((r0 >> 1) & 3);
    const long aRow0 = (long)(m * 128 + r0) * astr;
    const long aRow1 = (long)(m * 128 + r1) * astr;
    const long bRow = (long)(cc * 64 + r0) * KH + kg0;

    floatx4 acc[4][2];
    const floatx4 z4 = {0.f, 0.f, 0.f, 0.f};
#pragma unroll
    for (int i = 0; i < 4; i++)
#pragma unroll
        for (int j = 0; j < 2; j++) acc[i][j] = z4;

    auto stage = [&](int bb, int k0) {
        gl_lds16(A + aRow0 + k0 + c4s * 8, &sA[bb][wave * 512]);
        gl_lds16(A + aRow1 + k0 + c4s * 8, &sA[bb][2048 + wave * 512]);
        gl_lds16(Bd + bRow + k0 + c4s * 8, &sB[bb][wave * 512]);
    };
    auto compute = [&](int bb) {
        bf16x8 af[4], bb2[2];
#pragma unroll
        for (int rt = 0; rt < 4; rt++)
            af[rt] = *(const bf16x8*)(&sA[bb][(wr * 64 + rt * 16 + l15) * 32 + koff]);
#pragma unroll
        for (int ct = 0; ct < 2; ct++)
            bb2[ct] = *(const bf16x8*)(&sB[bb][(wc * 32 + ct * 16 + l15) * 32 + koff]);
#pragma unroll
        for (int rt = 0; rt < 4; rt++)
#pragma unroll
            for (int ct = 0; ct < 2; ct++)
                acc[rt][ct] = __builtin_amdgcn_mfma_f32_16x16x32_bf16(af[rt], bb2[ct], acc[rt][ct], 0, 0, 0);
    };

    stage(0, 0);
    stage(1, 32);                          // 2 stages (6 loads) in flight
    int bb = 0;
    for (int ks = 0; ks < ksteps; ks++) {
        if (ks + 2 < ksteps) stage((bb + 2) % 3, (ks + 2) * 32);
        if (ks + 2 < ksteps)      asm volatile("s_waitcnt vmcnt(6)" ::: "memory");
        else if (ks + 1 < ksteps) asm volatile("s_waitcnt vmcnt(3)" ::: "memory");
        else                      asm volatile("s_waitcnt vmcnt(0)" ::: "memory");
        __builtin_amdgcn_s_barrier();
        asm volatile("" ::: "memory");
        compute(bb);
        asm volatile("" ::: "memory");
        __builtin_amdgcn_s_barrier();
        bb = (bb + 1) % 3;
    }

    // epilogue: atomicAdd fp32 tile into out[token][d]
#pragma unroll
    for (int rt = 0; rt < 4; rt++) {
        // token per result-row (wave-uniform srow base; per-thread via q,r)
        int tk[4];
#pragma unroll
        for (int r = 0; r < 4; r++) {
            int srow = wr * 64 + rt * 16 + q * 4 + r;
            tk[r] = routed ? tok_list[e * NTOK + m * 128 + srow] : (m * 128 + srow);
        }
#pragma unroll
        for (int ct = 0; ct < 2; ct++) {
            int mc = cc * 64 + wc * 32 + ct * 16 + l15;
#pragma unroll
            for (int r = 0; r < 4; r++)
                atomicAdd(&out[(long)tk[r] * DIM + mc], acc[rt][ct][r]);
        }
    }
}

// ---------------------------------------------------------------------------
extern "C" void kernel_launch(void* const* d_in, const int* in_sizes, int n_in,
                              void* d_out, int out_size, void* d_ws, size_t ws_size,
                              hipStream_t stream) {
    const float* x    = (const float*)d_in[0];
    const float* W_g  = (const float*)d_in[1];
    const float* Wg_e = (const float*)d_in[2];
    const float* Wu_e = (const float*)d_in[3];
    const float* Wd_e = (const float*)d_in[4];
    const float* Wg_s = (const float*)d_in[5];
    const float* Wu_s = (const float*)d_in[6];
    const float* Wd_s = (const float*)d_in[7];
    float* out = (float*)d_out;

    bf16* Xb = (bf16*)d_ws;                            // [2048,1024]
    bf16* Bg = Xb + (size_t)NTOK * DIM;                // [5120,1024]
    bf16* Bu = Bg + (size_t)KH * DIM;                  // [5120,1024]
    bf16* Bd = Bu + (size_t)KH * DIM;                  // [1024,5120]
    bf16* Hs = Bd + (size_t)DIM * KH;                  // [2048,1024]
    bf16* He = Hs + (size_t)NTOK * DSH;                // [5120,512] compacted
    int*  counts   = (int*)(He + (size_t)MAXROWS * DEXP);
    int*  offs     = counts + NEXP;
    int*  tok_list = offs + NEXP;                      // [8,2048]
    float* cw      = (float*)(tok_list + NEXP * NTOK); // [8,2048]
    int2* te       = (int2*)(cw + NEXP * NTOK);        // [2048]
    float2* tp     = (float2*)(te + NTOK);             // [2048]

    // out is accumulated into by down_all -> zero it first (overlaps pack)
    hipMemsetAsync(out, 0, (size_t)NTOK * DIM * sizeof(float), stream);
    pack_gate<<<PACKBLOCKS + NTOK / 2, 128, 0, stream>>>(
        Wg_s, Wu_s, Wg_e, Wu_e, Wd_s, Wd_e, x, W_g, Bg, Bu, Bd, Xb, te, tp);
    assign_kernel<<<1, 512, 0, stream>>>(te, tp, counts, offs, tok_list, cw);
    gu_all<<<1280, 256, 0, stream>>>(Xb, Bg, Bu, counts, offs, tok_list, cw, Hs, He);
    down_all<<<2304, 256, 0, stream>>>(Hs, He, Bd, counts, offs, tok_list, out);
}

// Round 7
// 230.080 us; speedup vs baseline: 1.1367x; 1.1367x over previous
//
#include <hip/hip_runtime.h>
#include <hip/hip_bf16.h>

#define NTOK 2048
#define DIM  1024
#define DEXP 512
#define NEXP 8
#define DSH  1024          // shared expert width
#define KH   5120          // DSH + NEXP*DEXP (packed Bg/Bu row count; Bd col count)
#define MAXROWS 5120       // compacted routed slots upper bound
#define PACKBLOCKS 3840    // 15.75M weight elems / 4096 per 64x64 tile

typedef __hip_bfloat16 bf16;
typedef __attribute__((ext_vector_type(8))) short bf16x8;
typedef __attribute__((ext_vector_type(4))) float floatx4;

// async global->LDS, 16B/lane. LDS dest = wave-uniform base + lane*16 (HW adds).
__device__ __forceinline__ void gl_lds16(const bf16* g, bf16* l) {
    __builtin_amdgcn_global_load_lds(
        (const __attribute__((address_space(1))) void*)g,
        (__attribute__((address_space(3))) void*)l, 16, 0, 0);
}

__device__ __forceinline__ float b2f(short s) {
    union { float f; unsigned u; } v;
    v.u = ((unsigned)(unsigned short)s) << 16;
    return v.f;
}

struct B4 { bf16 a, b, c, d; };   // 8-byte bf16 quad

// ---------------------------------------------------------------------------
// Fused weight-pack + gating kernel (128 threads/block).
//  blocks [0, PACKBLOCKS): transpose-pack fp32 -> bf16, 64x64 tiles, LDS-FREE:
//    each lane reads a column-segment (8 scalar fp32, lane-coalesced rows),
//    cvt in-register, writes one 16B bf16x8. Lane-pairing (h=tid>>1, kc=tid&1)
//    makes adjacent lanes write adjacent 16B -> full 32B write sectors.
//    No LDS, no syncthreads, no conflicts, high residency.
//  blocks [PACKBLOCKS, +NTOK/2): gating softmax/top-2 + x fp32->bf16 cast.
// ---------------------------------------------------------------------------
__global__ __launch_bounds__(128) void pack_gate(
        const float* __restrict__ Wg_s, const float* __restrict__ Wu_s,
        const float* __restrict__ Wg_e, const float* __restrict__ Wu_e,
        const float* __restrict__ Wd_s, const float* __restrict__ Wd_e,
        const float* __restrict__ x, const float* __restrict__ Wg,
        bf16* __restrict__ Bg, bf16* __restrict__ Bu, bf16* __restrict__ Bd,
        bf16* __restrict__ Xb, int2* __restrict__ te, float2* __restrict__ tp) {
    int b = blockIdx.x;
    const int tid = threadIdx.x;
    if (b < PACKBLOCKS) {
        // ---- pack: src [R][C] fp32, dst[h = src col][k = src row] bf16 ----
        const float* src; bf16* dst; int C; long dstStride, dstBase; int tilesX;
        if (b < 256)        { src = Wg_s; dst = Bg; C = 1024; dstStride = 1024; dstBase = 0; tilesX = 16; }
        else if (b < 1280)  { int z = (b - 256) >> 7; b = (b - 256) & 127;
                              src = Wg_e + (long)z * DIM * DEXP; dst = Bg; C = 512;
                              dstStride = 1024; dstBase = (long)(DSH + z * DEXP) * 1024; tilesX = 8; }
        else if (b < 1536)  { b -= 1280; src = Wu_s; dst = Bu; C = 1024; dstStride = 1024; dstBase = 0; tilesX = 16; }
        else if (b < 2560)  { int z = (b - 1536) >> 7; b = (b - 1536) & 127;
                              src = Wu_e + (long)z * DIM * DEXP; dst = Bu; C = 512;
                              dstStride = 1024; dstBase = (long)(DSH + z * DEXP) * 1024; tilesX = 8; }
        else if (b < 2816)  { b -= 2560; src = Wd_s; dst = Bd; C = 1024; dstStride = KH; dstBase = 0; tilesX = 16; }
        else                { int z = (b - 2816) >> 7; b = (b - 2816) & 127;
                              src = Wd_e + (long)z * DEXP * DIM; dst = Bd; C = 1024;
                              dstStride = KH; dstBase = DSH + (long)z * DEXP; tilesX = 16; }
        const int tileX = b & (tilesX - 1), tileY = b / tilesX;
        const int c0 = tileX * 64, r0 = tileY * 64;

        const int h2 = tid >> 1;           // 0..63: dst row (src col)
        const int kp = tid & 1;            // lane-pair: adjacent 16B chunks
        const float* colBase = src + c0 + h2;
#pragma unroll
        for (int i = 0; i < 4; i++) {
            const int k8 = (i * 2 + kp) * 8;           // k-chunk base 0..56
            const float* s0 = colBase + (long)(r0 + k8) * C;
            union { unsigned short us[8]; bf16x8 v8; } o;
#pragma unroll
            for (int j = 0; j < 8; j++) {
                union { float f; unsigned u; } cv;
                cv.f = s0[(long)j * C];
                // round-to-nearest-even fp32->bf16 (match __float2bfloat16)
                unsigned r = (cv.u + 0x7fff + ((cv.u >> 16) & 1));
                o.us[j] = (unsigned short)((cv.u & 0x7f800000) == 0x7f800000
                                           ? (cv.u >> 16) | ((cv.u & 0xffff) ? 0x40 : 0)
                                           : r >> 16);
            }
            *(bf16x8*)(dst + dstBase + (long)(c0 + h2) * dstStride + r0 + k8) = o.v8;
        }
    } else {
        // ---- gating: one wave/token, fp32 logits -> softmax -> top-2 ----
        int t = (b - PACKBLOCKS) * 2 + (tid >> 6);
        int lane = tid & 63;
        const float* xr = x + (long)t * DIM;
        bf16* xo = Xb + (long)t * DIM;
        float acc[NEXP] = {0.f, 0.f, 0.f, 0.f, 0.f, 0.f, 0.f, 0.f};
#pragma unroll
        for (int i = 0; i < 4; i++) {
            int d = lane * 4 + i * 256;
            float4 xv = *(const float4*)(xr + d);
            B4 o{__float2bfloat16(xv.x), __float2bfloat16(xv.y),
                 __float2bfloat16(xv.z), __float2bfloat16(xv.w)};
            *(B4*)(xo + d) = o;
#pragma unroll
            for (int j = 0; j < 4; j++) {
                float xs = (j == 0) ? xv.x : (j == 1) ? xv.y : (j == 2) ? xv.z : xv.w;
                float4 w0 = *(const float4*)(Wg + (d + j) * NEXP);
                float4 w1 = *(const float4*)(Wg + (d + j) * NEXP + 4);
                acc[0] += xs * w0.x; acc[1] += xs * w0.y; acc[2] += xs * w0.z; acc[3] += xs * w0.w;
                acc[4] += xs * w1.x; acc[5] += xs * w1.y; acc[6] += xs * w1.z; acc[7] += xs * w1.w;
            }
        }
#pragma unroll
        for (int e = 0; e < NEXP; e++)
#pragma unroll
            for (int off = 32; off; off >>= 1)
                acc[e] += __shfl_xor(acc[e], off);
        if (lane == 0) {
            float m = acc[0];
#pragma unroll
            for (int e = 1; e < NEXP; e++) m = fmaxf(m, acc[e]);
            float p[NEXP], s = 0.f;
#pragma unroll
            for (int e = 0; e < NEXP; e++) { p[e] = expf(acc[e] - m); s += p[e]; }
            float inv = 1.f / s;
#pragma unroll
            for (int e = 0; e < NEXP; e++) p[e] *= inv;
            int i1 = 0;
#pragma unroll
            for (int e = 1; e < NEXP; e++) if (p[e] > p[i1]) i1 = e;   // strict >: lowest idx on tie
            int i2 = (i1 == 0) ? 1 : 0;
#pragma unroll
            for (int e = 0; e < NEXP; e++) if (e != i1 && p[e] > p[i2]) i2 = e;
            te[t] = make_int2(i1, i2);
            tp[t] = make_float2(p[i1], p[i2]);
        }
    }
}

// ---------------------------------------------------------------------------
// Phase-2 slot assignment: 1 block, 8 waves; wave e scans all tokens with
// ballot prefix -> deterministic slots. Zero atomics. Also zeroes the pad
// slots (token 0, weight 0) so no separate memset dispatch is needed.
// ---------------------------------------------------------------------------
__global__ __launch_bounds__(512) void assign_kernel(const int2* __restrict__ te,
                                                     const float2* __restrict__ tp,
                                                     int* __restrict__ counts,
                                                     int* __restrict__ offs,
                                                     int* __restrict__ tok_list,
                                                     float* __restrict__ cw,
                                                     int* __restrict__ s1a,
                                                     int* __restrict__ s2a) {
    __shared__ int cnt[NEXP];
    const int e = threadIdx.x >> 6;
    const int lane = threadIdx.x & 63;
    int base = 0;
    for (int t0 = 0; t0 < NTOK; t0 += 64) {
        int t = t0 + lane;
        int2 ee = te[t];
        bool m1 = (ee.x == e), m2 = (ee.y == e);
        bool mt = m1 || m2;
        unsigned long long mask = __ballot(mt);
        int pre = __popcll(mask & ((1ull << lane) - 1ull));
        if (mt) {
            int slot = base + pre;
            tok_list[e * NTOK + slot] = t;
            float2 pp = tp[t];
            cw[e * NTOK + slot] = m1 ? pp.x : pp.y;
            if (m1) s1a[t] = slot; else s2a[t] = slot;
        }
        base += __popcll(mask);
    }
    // zero pad slots up to the 128-rounded count (read as token 0 / weight 0)
    int rounded = (base + 127) & ~127;
    for (int s = base + lane; s < rounded; s += 64) {
        tok_list[e * NTOK + s] = 0;
        cw[e * NTOK + s] = 0.f;
    }
    if (lane == 0) cnt[e] = base;
    __syncthreads();
    if (threadIdx.x == 0) {
        int o = 0;
#pragma unroll
        for (int i = 0; i < NEXP; i++) {
            counts[i] = cnt[i];
            offs[i] = o;
            o += (cnt[i] + 127) & ~127;
        }
    }
}

// ---------------------------------------------------------------------------
// Unified gate+up SwiGLU GEMM (shared + gathered routed), tile 128x64, BK=32,
// 4 waves 2x2. XOR-swizzled LDS -> 0 conflicts.
// T3+T4: 3 LDS buffers, counted vmcnt, never drains to 0 mid-loop.
// (R3-proven structure, measured 40.8us.)
// ---------------------------------------------------------------------------
__global__ __launch_bounds__(256) void gu_all(const bf16* __restrict__ X,
                                              const bf16* __restrict__ Bg,
                                              const bf16* __restrict__ Bu,
                                              const int* __restrict__ counts,
                                              const int* __restrict__ offs,
                                              const int* __restrict__ tok_list,
                                              const float* __restrict__ cw,
                                              bf16* __restrict__ Hs,
                                              bf16* __restrict__ He) {
    __shared__ __align__(16) bf16 sA[3][128 * 32];
    __shared__ __align__(16) bf16 sBg[3][64 * 32];
    __shared__ __align__(16) bf16 sBu[3][64 * 32];

    const int b = blockIdx.x;
    const bool routed = b < 1024;
    int e = 0, m, c;
    if (routed) {
        e = b >> 7; m = (b >> 3) & 15; c = b & 7;
        if (m * 128 >= counts[e]) return;
    } else {
        int bs = b - 1024; m = bs >> 4; c = bs & 15;
    }
    const int so = routed ? offs[e] : 0;               // compacted slot base
    const int colB0 = routed ? (DSH + e * DEXP + c * 64) : c * 64;

    const int tid = threadIdx.x;
    const int wave = tid >> 6, lane = tid & 63;
    const int wr = wave >> 1, wc = wave & 1;
    const int q = lane >> 4, l15 = lane & 15;
    const int koff = (q ^ ((l15 >> 1) & 3)) * 8;       // swizzled fragment read

    const int r0 = tid >> 2, c4 = tid & 3;
    const int r1 = r0 + 64;
    const int c4s = c4 ^ ((r0 >> 1) & 3);
    long aRow0, aRow1;
    if (routed) {
        const int* tl = tok_list + e * NTOK + m * 128;
        aRow0 = (long)tl[r0] * DIM;
        aRow1 = (long)tl[r1] * DIM;
    } else {
        aRow0 = (long)(m * 128 + r0) * DIM;
        aRow1 = (long)(m * 128 + r1) * DIM;
    }
    const long bRow = (long)(colB0 + r0) * DIM;

    floatx4 accG[4][2], accU[4][2];
    const floatx4 z4 = {0.f, 0.f, 0.f, 0.f};
#pragma unroll
    for (int i = 0; i < 4; i++)
#pragma unroll
        for (int j = 0; j < 2; j++) { accG[i][j] = z4; accU[i][j] = z4; }

    auto stage = [&](int bb, int k0) {
        gl_lds16(X + aRow0 + k0 + c4s * 8, &sA[bb][wave * 512]);
        gl_lds16(X + aRow1 + k0 + c4s * 8, &sA[bb][2048 + wave * 512]);
        gl_lds16(Bg + bRow + k0 + c4s * 8, &sBg[bb][wave * 512]);
        gl_lds16(Bu + bRow + k0 + c4s * 8, &sBu[bb][wave * 512]);
    };
    auto compute = [&](int bb) {
        bf16x8 af[4], bgv[2], buv[2];
#pragma unroll
        for (int rt = 0; rt < 4; rt++)
            af[rt] = *(const bf16x8*)(&sA[bb][(wr * 64 + rt * 16 + l15) * 32 + koff]);
#pragma unroll
        for (int ct = 0; ct < 2; ct++) {
            int cb = (wc * 32 + ct * 16 + l15) * 32 + koff;
            bgv[ct] = *(const bf16x8*)(&sBg[bb][cb]);
            buv[ct] = *(const bf16x8*)(&sBu[bb][cb]);
        }
#pragma unroll
        for (int rt = 0; rt < 4; rt++)
#pragma unroll
            for (int ct = 0; ct < 2; ct++) {
                accG[rt][ct] = __builtin_amdgcn_mfma_f32_16x16x32_bf16(af[rt], bgv[ct], accG[rt][ct], 0, 0, 0);
                accU[rt][ct] = __builtin_amdgcn_mfma_f32_16x16x32_bf16(af[rt], buv[ct], accU[rt][ct], 0, 0, 0);
            }
    };

    const int NS = DIM / 32;               // 32 K-steps
    stage(0, 0);
    stage(1, 32);                          // 2 stages in flight
    int bb = 0;
    for (int ks = 0; ks < NS; ks++) {
        if (ks + 2 < NS) stage((bb + 2) % 3, (ks + 2) * 32);
        // wait: buffer ks's 4 loads done; stages ks+1,ks+2 stay in flight
        if (ks + 2 < NS)      asm volatile("s_waitcnt vmcnt(8)" ::: "memory");
        else if (ks + 1 < NS) asm volatile("s_waitcnt vmcnt(4)" ::: "memory");
        else                  asm volatile("s_waitcnt vmcnt(0)" ::: "memory");
        __builtin_amdgcn_s_barrier();      // raw: no compiler vmcnt(0) drain
        asm volatile("" ::: "memory");
        compute(bb);
        asm volatile("" ::: "memory");
        __builtin_amdgcn_s_barrier();      // protect buffer bb from next stage
        bb = (bb + 1) % 3;
    }

    // epilogue: silu(g)*u*w  (C/D layout: col=lane&15, row=q*4+reg)
    float wv[4][4];
#pragma unroll
    for (int rt = 0; rt < 4; rt++)
#pragma unroll
        for (int r = 0; r < 4; r++) {
            int srow = wr * 64 + rt * 16 + q * 4 + r;
            wv[rt][r] = routed ? cw[e * NTOK + m * 128 + srow] : 1.0f;
        }
#pragma unroll
    for (int rt = 0; rt < 4; rt++)
#pragma unroll
        for (int ct = 0; ct < 2; ct++)
#pragma unroll
            for (int r = 0; r < 4; r++) {
                int srow = wr * 64 + rt * 16 + q * 4 + r;
                int colLoc = c * 64 + wc * 32 + ct * 16 + l15;
                float g = accG[rt][ct][r];
                float u = accU[rt][ct][r];
                float h = (g / (1.f + __expf(-g))) * u * wv[rt][r];
                if (routed)
                    He[(long)(so + m * 128 + srow) * DEXP + colLoc] = __float2bfloat16(h);
                else
                    Hs[(long)(m * 128 + srow) * DSH + colLoc] = __float2bfloat16(h);
            }
}

// ---------------------------------------------------------------------------
// Unified down GEMM, NO atomics: dense bf16 partial outputs (R3-proven).
// Counted-vmcnt 3-buffer pipeline (3 loads/stage -> vmcnt(6)).
// ---------------------------------------------------------------------------
__global__ __launch_bounds__(256) void down_all(const bf16* __restrict__ Hs,
                                                const bf16* __restrict__ He,
                                                const bf16* __restrict__ Bd,
                                                const int* __restrict__ counts,
                                                const int* __restrict__ offs,
                                                bf16* __restrict__ Ys,
                                                bf16* __restrict__ Ye) {
    __shared__ __align__(16) bf16 sA[3][128 * 32];
    __shared__ __align__(16) bf16 sB[3][64 * 32];

    const int b = blockIdx.x;
    const bool routed = b < 2048;
    int e = 0, m, cc;
    if (routed) {
        e = b >> 8; m = (b >> 4) & 15; cc = b & 15;
        if (m * 128 >= counts[e]) return;
    } else {
        int bs = b - 2048; m = bs >> 4; cc = bs & 15;
    }
    const int so = routed ? offs[e] : 0;
    const bf16* A = routed ? He + (long)so * DEXP : Hs;
    bf16* Y = routed ? Ye + (long)so * DIM : Ys;
    const int astr = routed ? DEXP : DSH;
    const int ksteps = routed ? (DEXP / 32) : (DSH / 32);
    const int kg0 = routed ? (DSH + e * DEXP) : 0;     // K-offset within Bd rows

    const int tid = threadIdx.x;
    const int wave = tid >> 6, lane = tid & 63;
    const int wr = wave >> 1, wc = wave & 1;
    const int q = lane >> 4, l15 = lane & 15;
    const int koff = (q ^ ((l15 >> 1) & 3)) * 8;

    const int r0 = tid >> 2, c4 = tid & 3;
    const int r1 = r0 + 64;
    const int c4s = c4 ^ ((r0 >> 1) & 3);
    const long aRow0 = (long)(m * 128 + r0) * astr;
    const long aRow1 = (long)(m * 128 + r1) * astr;
    const long bRow = (long)(cc * 64 + r0) * KH + kg0;

    floatx4 acc[4][2];
    const floatx4 z4 = {0.f, 0.f, 0.f, 0.f};
#pragma unroll
    for (int i = 0; i < 4; i++)
#pragma unroll
        for (int j = 0; j < 2; j++) acc[i][j] = z4;

    auto stage = [&](int bb, int k0) {
        gl_lds16(A + aRow0 + k0 + c4s * 8, &sA[bb][wave * 512]);
        gl_lds16(A + aRow1 + k0 + c4s * 8, &sA[bb][2048 + wave * 512]);
        gl_lds16(Bd + bRow + k0 + c4s * 8, &sB[bb][wave * 512]);
    };
    auto compute = [&](int bb) {
        bf16x8 af[4], bb2[2];
#pragma unroll
        for (int rt = 0; rt < 4; rt++)
            af[rt] = *(const bf16x8*)(&sA[bb][(wr * 64 + rt * 16 + l15) * 32 + koff]);
#pragma unroll
        for (int ct = 0; ct < 2; ct++)
            bb2[ct] = *(const bf16x8*)(&sB[bb][(wc * 32 + ct * 16 + l15) * 32 + koff]);
#pragma unroll
        for (int rt = 0; rt < 4; rt++)
#pragma unroll
            for (int ct = 0; ct < 2; ct++)
                acc[rt][ct] = __builtin_amdgcn_mfma_f32_16x16x32_bf16(af[rt], bb2[ct], acc[rt][ct], 0, 0, 0);
    };

    stage(0, 0);
    stage(1, 32);                          // 2 stages in flight
    int bb = 0;
    for (int ks = 0; ks < ksteps; ks++) {
        if (ks + 2 < ksteps) stage((bb + 2) % 3, (ks + 2) * 32);
        if (ks + 2 < ksteps)      asm volatile("s_waitcnt vmcnt(6)" ::: "memory");
        else if (ks + 1 < ksteps) asm volatile("s_waitcnt vmcnt(3)" ::: "memory");
        else                      asm volatile("s_waitcnt vmcnt(0)" ::: "memory");
        __builtin_amdgcn_s_barrier();
        asm volatile("" ::: "memory");
        compute(bb);
        asm volatile("" ::: "memory");
        __builtin_amdgcn_s_barrier();
        bb = (bb + 1) % 3;
    }

#pragma unroll
    for (int rt = 0; rt < 4; rt++)
#pragma unroll
        for (int ct = 0; ct < 2; ct++)
#pragma unroll
            for (int r = 0; r < 4; r++) {
                int srow = wr * 64 + rt * 16 + q * 4 + r;
                int mc = cc * 64 + wc * 32 + ct * 16 + l15;
                Y[(long)(m * 128 + srow) * DIM + mc] = __float2bfloat16(acc[rt][ct][r]);
            }
}

// ---------------------------------------------------------------------------
// Final gather-combine: out[t] = Ys[t] + Ye[offs[e1]+s1] + Ye[offs[e2]+s2].
// ---------------------------------------------------------------------------
__global__ __launch_bounds__(256) void combine_kernel(const bf16* __restrict__ Ys,
                                                      const bf16* __restrict__ Ye,
                                                      const int2* __restrict__ te,
                                                      const int* __restrict__ s1a,
                                                      const int* __restrict__ s2a,
                                                      const int* __restrict__ offs,
                                                      float* __restrict__ out) {
    int idx = blockIdx.x * 256 + threadIdx.x;   // NTOK*DIM/8 total
    int t = idx >> 7;
    int d = (idx & 127) * 8;
    int2 ee = te[t];
    long r1 = (long)(offs[ee.x] + s1a[t]);
    long r2 = (long)(offs[ee.y] + s2a[t]);
    bf16x8 a = *(const bf16x8*)(Ys + (long)t * DIM + d);
    bf16x8 p = *(const bf16x8*)(Ye + r1 * DIM + d);
    bf16x8 r = *(const bf16x8*)(Ye + r2 * DIM + d);
    float* o = out + (long)t * DIM + d;
#pragma unroll
    for (int i = 0; i < 8; i++)
        o[i] = b2f(a[i]) + b2f(p[i]) + b2f(r[i]);
}

// ---------------------------------------------------------------------------
extern "C" void kernel_launch(void* const* d_in, const int* in_sizes, int n_in,
                              void* d_out, int out_size, void* d_ws, size_t ws_size,
                              hipStream_t stream) {
    const float* x    = (const float*)d_in[0];
    const float* W_g  = (const float*)d_in[1];
    const float* Wg_e = (const float*)d_in[2];
    const float* Wu_e = (const float*)d_in[3];
    const float* Wd_e = (const float*)d_in[4];
    const float* Wg_s = (const float*)d_in[5];
    const float* Wu_s = (const float*)d_in[6];
    const float* Wd_s = (const float*)d_in[7];
    float* out = (float*)d_out;

    bf16* Xb = (bf16*)d_ws;                            // [2048,1024]
    bf16* Bg = Xb + (size_t)NTOK * DIM;                // [5120,1024]
    bf16* Bu = Bg + (size_t)KH * DIM;                  // [5120,1024]
    bf16* Bd = Bu + (size_t)KH * DIM;                  // [1024,5120]
    bf16* Hs = Bd + (size_t)DIM * KH;                  // [2048,1024]
    bf16* He = Hs + (size_t)NTOK * DSH;                // [5120,512] compacted
    bf16* Ys = He + (size_t)MAXROWS * DEXP;            // [2048,1024]
    bf16* Ye = Ys + (size_t)NTOK * DIM;                // [5120,1024] compacted
    int*  counts   = (int*)(Ye + (size_t)MAXROWS * DIM);
    int*  offs     = counts + NEXP;
    int*  tok_list = offs + NEXP;                      // [8,2048]
    float* cw      = (float*)(tok_list + NEXP * NTOK); // [8,2048]
    int*  s1a      = (int*)(cw + NEXP * NTOK);         // [2048]
    int*  s2a      = s1a + NTOK;                       // [2048]
    int2* te       = (int2*)(s2a + NTOK);              // [2048]
    float2* tp     = (float2*)(te + NTOK);             // [2048]

    pack_gate<<<PACKBLOCKS + NTOK / 2, 128, 0, stream>>>(
        Wg_s, Wu_s, Wg_e, Wu_e, Wd_s, Wd_e, x, W_g, Bg, Bu, Bd, Xb, te, tp);
    assign_kernel<<<1, 512, 0, stream>>>(te, tp, counts, offs, tok_list, cw, s1a, s2a);
    gu_all<<<1280, 256, 0, stream>>>(Xb, Bg, Bu, counts, offs, tok_list, cw, Hs, He);
    down_all<<<2304, 256, 0, stream>>>(Hs, He, Bd, counts, offs, Ys, Ye);
    combine_kernel<<<NTOK * DIM / 8 / 256, 256, 0, stream>>>(Ys, Ye, te, s1a, s2a, offs, out);
}

// Round 8
// 201.421 us; speedup vs baseline: 1.2984x; 1.1423x over previous
//
#include <hip/hip_runtime.h>
#include <hip/hip_bf16.h>

#define NTOK 2048
#define DIM  1024
#define DEXP 512
#define NEXP 8
#define DSH  1024          // shared expert width
#define KH   5120          // DSH + NEXP*DEXP (packed Bg/Bu row count; Bd col count)
#define MAXROWS 5120       // compacted routed slots upper bound
#define PACKBLOCKS 2560    // Bg+Bu tiles only (Bd pack folded into gu_all)

typedef __hip_bfloat16 bf16;
typedef __attribute__((ext_vector_type(8))) short bf16x8;
typedef __attribute__((ext_vector_type(4))) float floatx4;

// async global->LDS, 16B/lane. LDS dest = wave-uniform base + lane*16 (HW adds).
__device__ __forceinline__ void gl_lds16(const bf16* g, bf16* l) {
    __builtin_amdgcn_global_load_lds(
        (const __attribute__((address_space(1))) void*)g,
        (__attribute__((address_space(3))) void*)l, 16, 0, 0);
}

__device__ __forceinline__ float b2f(short s) {
    union { float f; unsigned u; } v;
    v.u = ((unsigned)(unsigned short)s) << 16;
    return v.f;
}

struct B4 { bf16 a, b, c, d; };   // 8-byte bf16 quad

// ---------------------------------------------------------------------------
// Fused Bg/Bu-pack + gating kernel (128 threads/block). R2-proven LDS pack:
// 8 float4 loads/lane in flight, cvt to bf16 BEFORE LDS, stride-35-dword LDS.
// Bd pack is folded into gu_all (fills gu_all's idle CU capacity).
// ---------------------------------------------------------------------------
__global__ __launch_bounds__(128) void pack_gate(
        const float* __restrict__ Wg_s, const float* __restrict__ Wu_s,
        const float* __restrict__ Wg_e, const float* __restrict__ Wu_e,
        const float* __restrict__ x, const float* __restrict__ Wg,
        bf16* __restrict__ Bg, bf16* __restrict__ Bu,
        bf16* __restrict__ Xb, int2* __restrict__ te, float2* __restrict__ tp) {
    int b = blockIdx.x;
    const int tid = threadIdx.x;
    if (b < PACKBLOCKS) {
        // ---- pack: src [R][C] fp32, dst[h = src col][k = src row] bf16 ----
        __shared__ unsigned lt[64][35];
        const float* src; bf16* dst; int C; long dstBase; int tilesX;
        if (b < 256)        { src = Wg_s; dst = Bg; C = 1024; dstBase = 0; tilesX = 16; }
        else if (b < 1280)  { int z = (b - 256) >> 7; b = (b - 256) & 127;
                              src = Wg_e + (long)z * DIM * DEXP; dst = Bg; C = 512;
                              dstBase = (long)(DSH + z * DEXP) * 1024; tilesX = 8; }
        else if (b < 1536)  { b -= 1280; src = Wu_s; dst = Bu; C = 1024; dstBase = 0; tilesX = 16; }
        else                { int z = (b - 1536) >> 7; b = (b - 1536) & 127;
                              src = Wu_e + (long)z * DIM * DEXP; dst = Bu; C = 512;
                              dstBase = (long)(DSH + z * DEXP) * 1024; tilesX = 8; }
        const int tileX = b & (tilesX - 1), tileY = b / tilesX;
        const int c0 = tileX * 64, r0 = tileY * 64;

        // load 64x64 fp32, 8 independent float4/lane, cvt->bf16, pack to LDS
        const int lrow = tid >> 4, lch = tid & 15;
#pragma unroll
        for (int i = 0; i < 8; i++) {
            int row = lrow + i * 8;
            float4 v = *(const float4*)(src + (long)(r0 + row) * C + c0 + lch * 4);
            union { bf16 h[2]; unsigned u; } p0, p1;
            p0.h[0] = __float2bfloat16(v.x); p0.h[1] = __float2bfloat16(v.y);
            p1.h[0] = __float2bfloat16(v.z); p1.h[1] = __float2bfloat16(v.w);
            lt[row][lch * 2]     = p0.u;
            lt[row][lch * 2 + 1] = p1.u;
        }
        __syncthreads();
        // transposed store: each lane emits one 16B bf16x8 (8 k of one h)
        const int kc = tid & 7;
#pragma unroll
        for (int i = 0; i < 4; i++) {
            int h = (tid >> 3) + i * 16;
            union { unsigned short s[8]; bf16x8 v8; } o;
#pragma unroll
            for (int j = 0; j < 8; j++)
                o.s[j] = ((const unsigned short*)lt[kc * 8 + j])[h];
            *(bf16x8*)(dst + dstBase + (long)(c0 + h) * 1024 + r0 + kc * 8) = o.v8;
        }
    } else {
        // ---- gating: one wave/token, fp32 logits -> softmax -> top-2 ----
        int t = (b - PACKBLOCKS) * 2 + (tid >> 6);
        int lane = tid & 63;
        const float* xr = x + (long)t * DIM;
        bf16* xo = Xb + (long)t * DIM;
        float acc[NEXP] = {0.f, 0.f, 0.f, 0.f, 0.f, 0.f, 0.f, 0.f};
#pragma unroll
        for (int i = 0; i < 4; i++) {
            int d = lane * 4 + i * 256;
            float4 xv = *(const float4*)(xr + d);
            B4 o{__float2bfloat16(xv.x), __float2bfloat16(xv.y),
                 __float2bfloat16(xv.z), __float2bfloat16(xv.w)};
            *(B4*)(xo + d) = o;
#pragma unroll
            for (int j = 0; j < 4; j++) {
                float xs = (j == 0) ? xv.x : (j == 1) ? xv.y : (j == 2) ? xv.z : xv.w;
                float4 w0 = *(const float4*)(Wg + (d + j) * NEXP);
                float4 w1 = *(const float4*)(Wg + (d + j) * NEXP + 4);
                acc[0] += xs * w0.x; acc[1] += xs * w0.y; acc[2] += xs * w0.z; acc[3] += xs * w0.w;
                acc[4] += xs * w1.x; acc[5] += xs * w1.y; acc[6] += xs * w1.z; acc[7] += xs * w1.w;
            }
        }
#pragma unroll
        for (int e = 0; e < NEXP; e++)
#pragma unroll
            for (int off = 32; off; off >>= 1)
                acc[e] += __shfl_xor(acc[e], off);
        if (lane == 0) {
            float m = acc[0];
#pragma unroll
            for (int e = 1; e < NEXP; e++) m = fmaxf(m, acc[e]);
            float p[NEXP], s = 0.f;
#pragma unroll
            for (int e = 0; e < NEXP; e++) { p[e] = expf(acc[e] - m); s += p[e]; }
            float inv = 1.f / s;
#pragma unroll
            for (int e = 0; e < NEXP; e++) p[e] *= inv;
            int i1 = 0;
#pragma unroll
            for (int e = 1; e < NEXP; e++) if (p[e] > p[i1]) i1 = e;   // strict >: lowest idx on tie
            int i2 = (i1 == 0) ? 1 : 0;
#pragma unroll
            for (int e = 0; e < NEXP; e++) if (e != i1 && p[e] > p[i2]) i2 = e;
            te[t] = make_int2(i1, i2);
            tp[t] = make_float2(p[i1], p[i2]);
        }
    }
}

// ---------------------------------------------------------------------------
// Phase-2 slot assignment: 1 block, 8 waves; wave e scans all tokens with
// ballot prefix -> deterministic slots. Zero atomics. Also zeroes the pad
// slots (token 0, weight 0) so no separate memset dispatch is needed.
// ---------------------------------------------------------------------------
__global__ __launch_bounds__(512) void assign_kernel(const int2* __restrict__ te,
                                                     const float2* __restrict__ tp,
                                                     int* __restrict__ counts,
                                                     int* __restrict__ offs,
                                                     int* __restrict__ tok_list,
                                                     float* __restrict__ cw,
                                                     int* __restrict__ s1a,
                                                     int* __restrict__ s2a) {
    __shared__ int cnt[NEXP];
    const int e = threadIdx.x >> 6;
    const int lane = threadIdx.x & 63;
    int base = 0;
    for (int t0 = 0; t0 < NTOK; t0 += 64) {
        int t = t0 + lane;
        int2 ee = te[t];
        bool m1 = (ee.x == e), m2 = (ee.y == e);
        bool mt = m1 || m2;
        unsigned long long mask = __ballot(mt);
        int pre = __popcll(mask & ((1ull << lane) - 1ull));
        if (mt) {
            int slot = base + pre;
            tok_list[e * NTOK + slot] = t;
            float2 pp = tp[t];
            cw[e * NTOK + slot] = m1 ? pp.x : pp.y;
            if (m1) s1a[t] = slot; else s2a[t] = slot;
        }
        base += __popcll(mask);
    }
    // zero pad slots up to the 128-rounded count (read as token 0 / weight 0)
    int rounded = (base + 127) & ~127;
    for (int s = base + lane; s < rounded; s += 64) {
        tok_list[e * NTOK + s] = 0;
        cw[e * NTOK + s] = 0.f;
    }
    if (lane == 0) cnt[e] = base;
    __syncthreads();
    if (threadIdx.x == 0) {
        int o = 0;
#pragma unroll
        for (int i = 0; i < NEXP; i++) {
            counts[i] = cnt[i];
            offs[i] = o;
            o += (cnt[i] + 127) & ~127;
        }
    }
}

// ---------------------------------------------------------------------------
// Unified gate+up SwiGLU GEMM (shared + gathered routed), tile 128x64, BK=32,
// 4 waves 2x2, XOR-swizzled LDS, 3-buffer counted-vmcnt pipeline (R3-proven).
// PLUS: blocks >= 1280 pack Bd (Wd_s/Wd_e fp32 -> transposed bf16) — zero
// dependency on GEMM inputs/outputs; they backfill the idle CU capacity of
// this latency-bound dispatch. Only down_all needs Bd (next kernel).
// ---------------------------------------------------------------------------
__global__ __launch_bounds__(256) void gu_all(const bf16* __restrict__ X,
                                              const bf16* __restrict__ Bg,
                                              const bf16* __restrict__ Bu,
                                              const int* __restrict__ counts,
                                              const int* __restrict__ offs,
                                              const int* __restrict__ tok_list,
                                              const float* __restrict__ cw,
                                              const float* __restrict__ Wd_s,
                                              const float* __restrict__ Wd_e,
                                              bf16* __restrict__ Bd,
                                              bf16* __restrict__ Hs,
                                              bf16* __restrict__ He) {
    __shared__ __align__(16) bf16 sA[3][128 * 32];
    __shared__ __align__(16) bf16 sBg[3][64 * 32];
    __shared__ __align__(16) bf16 sBu[3][64 * 32];

    const int b = blockIdx.x;

    if (b >= 1280) {
        // ---- Bd pack tile (256 threads), LDS scratch aliases sA ----
        unsigned* lt = (unsigned*)&sA[0][0];           // [64][35] dwords, 8.75KB
        int pb = b - 1280;
        const float* src; long dstBase; int tileX, tileY;
        if (pb < 256) {                                // Wd_s [1024][1024] -> Bd[d][k]
            src = Wd_s; dstBase = 0;
            tileX = pb & 15; tileY = pb >> 4;          // 16x16 tiles
        } else {                                       // Wd_e[z] [512][1024] -> Bd[d][DSH+z*512+k]
            int q = pb - 256; int z = q >> 7; q &= 127;
            src = Wd_e + (long)z * DEXP * DIM;
            dstBase = DSH + (long)z * DEXP;
            tileX = q & 15; tileY = q >> 4;            // 8 rows x 16 cols of tiles
        }
        const int c0 = tileX * 64, r0 = tileY * 64;    // c0: src col (d), r0: src row (k)
        const int tid = threadIdx.x;
        const int lrow = tid >> 4, lch = tid & 15;     // 16 rows x 16 f4-chunks
#pragma unroll
        for (int i = 0; i < 4; i++) {
            int row = lrow + i * 16;
            float4 v = *(const float4*)(src + (long)(r0 + row) * DIM + c0 + lch * 4);
            union { bf16 h[2]; unsigned u; } p0, p1;
            p0.h[0] = __float2bfloat16(v.x); p0.h[1] = __float2bfloat16(v.y);
            p1.h[0] = __float2bfloat16(v.z); p1.h[1] = __float2bfloat16(v.w);
            lt[row * 35 + lch * 2]     = p0.u;
            lt[row * 35 + lch * 2 + 1] = p1.u;
        }
        __syncthreads();
        const int kc = tid & 7;
#pragma unroll
        for (int i = 0; i < 2; i++) {
            int h = (tid >> 3) + i * 32;               // dst row (src col d)
            union { unsigned short s[8]; bf16x8 v8; } o;
#pragma unroll
            for (int j = 0; j < 8; j++)
                o.s[j] = ((const unsigned short*)(lt + (kc * 8 + j) * 35))[h];
            *(bf16x8*)(Bd + (long)(c0 + h) * KH + dstBase + r0 + kc * 8) = o.v8;
        }
        return;
    }

    const bool routed = b < 1024;
    int e = 0, m, c;
    if (routed) {
        e = b >> 7; m = (b >> 3) & 15; c = b & 7;
        if (m * 128 >= counts[e]) return;
    } else {
        int bs = b - 1024; m = bs >> 4; c = bs & 15;
    }
    const int so = routed ? offs[e] : 0;               // compacted slot base
    const int colB0 = routed ? (DSH + e * DEXP + c * 64) : c * 64;

    const int tid = threadIdx.x;
    const int wave = tid >> 6, lane = tid & 63;
    const int wr = wave >> 1, wc = wave & 1;
    const int q = lane >> 4, l15 = lane & 15;
    const int koff = (q ^ ((l15 >> 1) & 3)) * 8;       // swizzled fragment read

    const int r0 = tid >> 2, c4 = tid & 3;
    const int r1 = r0 + 64;
    const int c4s = c4 ^ ((r0 >> 1) & 3);
    long aRow0, aRow1;
    if (routed) {
        const int* tl = tok_list + e * NTOK + m * 128;
        aRow0 = (long)tl[r0] * DIM;
        aRow1 = (long)tl[r1] * DIM;
    } else {
        aRow0 = (long)(m * 128 + r0) * DIM;
        aRow1 = (long)(m * 128 + r1) * DIM;
    }
    const long bRow = (long)(colB0 + r0) * DIM;

    floatx4 accG[4][2], accU[4][2];
    const floatx4 z4 = {0.f, 0.f, 0.f, 0.f};
#pragma unroll
    for (int i = 0; i < 4; i++)
#pragma unroll
        for (int j = 0; j < 2; j++) { accG[i][j] = z4; accU[i][j] = z4; }

    auto stage = [&](int bb, int k0) {
        gl_lds16(X + aRow0 + k0 + c4s * 8, &sA[bb][wave * 512]);
        gl_lds16(X + aRow1 + k0 + c4s * 8, &sA[bb][2048 + wave * 512]);
        gl_lds16(Bg + bRow + k0 + c4s * 8, &sBg[bb][wave * 512]);
        gl_lds16(Bu + bRow + k0 + c4s * 8, &sBu[bb][wave * 512]);
    };
    auto compute = [&](int bb) {
        bf16x8 af[4], bgv[2], buv[2];
#pragma unroll
        for (int rt = 0; rt < 4; rt++)
            af[rt] = *(const bf16x8*)(&sA[bb][(wr * 64 + rt * 16 + l15) * 32 + koff]);
#pragma unroll
        for (int ct = 0; ct < 2; ct++) {
            int cb = (wc * 32 + ct * 16 + l15) * 32 + koff;
            bgv[ct] = *(const bf16x8*)(&sBg[bb][cb]);
            buv[ct] = *(const bf16x8*)(&sBu[bb][cb]);
        }
#pragma unroll
        for (int rt = 0; rt < 4; rt++)
#pragma unroll
            for (int ct = 0; ct < 2; ct++) {
                accG[rt][ct] = __builtin_amdgcn_mfma_f32_16x16x32_bf16(af[rt], bgv[ct], accG[rt][ct], 0, 0, 0);
                accU[rt][ct] = __builtin_amdgcn_mfma_f32_16x16x32_bf16(af[rt], buv[ct], accU[rt][ct], 0, 0, 0);
            }
    };

    const int NS = DIM / 32;               // 32 K-steps
    stage(0, 0);
    stage(1, 32);                          // 2 stages in flight
    int bb = 0;
    for (int ks = 0; ks < NS; ks++) {
        if (ks + 2 < NS) stage((bb + 2) % 3, (ks + 2) * 32);
        // wait: buffer ks's 4 loads done; stages ks+1,ks+2 stay in flight
        if (ks + 2 < NS)      asm volatile("s_waitcnt vmcnt(8)" ::: "memory");
        else if (ks + 1 < NS) asm volatile("s_waitcnt vmcnt(4)" ::: "memory");
        else                  asm volatile("s_waitcnt vmcnt(0)" ::: "memory");
        __builtin_amdgcn_s_barrier();      // raw: no compiler vmcnt(0) drain
        asm volatile("" ::: "memory");
        compute(bb);
        asm volatile("" ::: "memory");
        __builtin_amdgcn_s_barrier();      // protect buffer bb from next stage
        bb = (bb + 1) % 3;
    }

    // epilogue: silu(g)*u*w  (C/D layout: col=lane&15, row=q*4+reg)
    float wv[4][4];
#pragma unroll
    for (int rt = 0; rt < 4; rt++)
#pragma unroll
        for (int r = 0; r < 4; r++) {
            int srow = wr * 64 + rt * 16 + q * 4 + r;
            wv[rt][r] = routed ? cw[e * NTOK + m * 128 + srow] : 1.0f;
        }
#pragma unroll
    for (int rt = 0; rt < 4; rt++)
#pragma unroll
        for (int ct = 0; ct < 2; ct++)
#pragma unroll
            for (int r = 0; r < 4; r++) {
                int srow = wr * 64 + rt * 16 + q * 4 + r;
                int colLoc = c * 64 + wc * 32 + ct * 16 + l15;
                float g = accG[rt][ct][r];
                float u = accU[rt][ct][r];
                float h = (g / (1.f + __expf(-g))) * u * wv[rt][r];
                if (routed)
                    He[(long)(so + m * 128 + srow) * DEXP + colLoc] = __float2bfloat16(h);
                else
                    Hs[(long)(m * 128 + srow) * DSH + colLoc] = __float2bfloat16(h);
            }
}

// ---------------------------------------------------------------------------
// Unified down GEMM, NO atomics: dense bf16 partial outputs (R3-proven).
// Counted-vmcnt 3-buffer pipeline (3 loads/stage -> vmcnt(6)).
// ---------------------------------------------------------------------------
__global__ __launch_bounds__(256) void down_all(const bf16* __restrict__ Hs,
                                                const bf16* __restrict__ He,
                                                const bf16* __restrict__ Bd,
                                                const int* __restrict__ counts,
                                                const int* __restrict__ offs,
                                                bf16* __restrict__ Ys,
                                                bf16* __restrict__ Ye) {
    __shared__ __align__(16) bf16 sA[3][128 * 32];
    __shared__ __align__(16) bf16 sB[3][64 * 32];

    const int b = blockIdx.x;
    const bool routed = b < 2048;
    int e = 0, m, cc;
    if (routed) {
        e = b >> 8; m = (b >> 4) & 15; cc = b & 15;
        if (m * 128 >= counts[e]) return;
    } else {
        int bs = b - 2048; m = bs >> 4; cc = bs & 15;
    }
    const int so = routed ? offs[e] : 0;
    const bf16* A = routed ? He + (long)so * DEXP : Hs;
    bf16* Y = routed ? Ye + (long)so * DIM : Ys;
    const int astr = routed ? DEXP : DSH;
    const int ksteps = routed ? (DEXP / 32) : (DSH / 32);
    const int kg0 = routed ? (DSH + e * DEXP) : 0;     // K-offset within Bd rows

    const int tid = threadIdx.x;
    const int wave = tid >> 6, lane = tid & 63;
    const int wr = wave >> 1, wc = wave & 1;
    const int q = lane >> 4, l15 = lane & 15;
    const int koff = (q ^ ((l15 >> 1) & 3)) * 8;

    const int r0 = tid >> 2, c4 = tid & 3;
    const int r1 = r0 + 64;
    const int c4s = c4 ^ ((r0 >> 1) & 3);
    const long aRow0 = (long)(m * 128 + r0) * astr;
    const long aRow1 = (long)(m * 128 + r1) * astr;
    const long bRow = (long)(cc * 64 + r0) * KH + kg0;

    floatx4 acc[4][2];
    const floatx4 z4 = {0.f, 0.f, 0.f, 0.f};
#pragma unroll
    for (int i = 0; i < 4; i++)
#pragma unroll
        for (int j = 0; j < 2; j++) acc[i][j] = z4;

    auto stage = [&](int bb, int k0) {
        gl_lds16(A + aRow0 + k0 + c4s * 8, &sA[bb][wave * 512]);
        gl_lds16(A + aRow1 + k0 + c4s * 8, &sA[bb][2048 + wave * 512]);
        gl_lds16(Bd + bRow + k0 + c4s * 8, &sB[bb][wave * 512]);
    };
    auto compute = [&](int bb) {
        bf16x8 af[4], bb2[2];
#pragma unroll
        for (int rt = 0; rt < 4; rt++)
            af[rt] = *(const bf16x8*)(&sA[bb][(wr * 64 + rt * 16 + l15) * 32 + koff]);
#pragma unroll
        for (int ct = 0; ct < 2; ct++)
            bb2[ct] = *(const bf16x8*)(&sB[bb][(wc * 32 + ct * 16 + l15) * 32 + koff]);
#pragma unroll
        for (int rt = 0; rt < 4; rt++)
#pragma unroll
            for (int ct = 0; ct < 2; ct++)
                acc[rt][ct] = __builtin_amdgcn_mfma_f32_16x16x32_bf16(af[rt], bb2[ct], acc[rt][ct], 0, 0, 0);
    };

    stage(0, 0);
    stage(1, 32);                          // 2 stages in flight
    int bb = 0;
    for (int ks = 0; ks < ksteps; ks++) {
        if (ks + 2 < ksteps) stage((bb + 2) % 3, (ks + 2) * 32);
        if (ks + 2 < ksteps)      asm volatile("s_waitcnt vmcnt(6)" ::: "memory");
        else if (ks + 1 < ksteps) asm volatile("s_waitcnt vmcnt(3)" ::: "memory");
        else                      asm volatile("s_waitcnt vmcnt(0)" ::: "memory");
        __builtin_amdgcn_s_barrier();
        asm volatile("" ::: "memory");
        compute(bb);
        asm volatile("" ::: "memory");
        __builtin_amdgcn_s_barrier();
        bb = (bb + 1) % 3;
    }

#pragma unroll
    for (int rt = 0; rt < 4; rt++)
#pragma unroll
        for (int ct = 0; ct < 2; ct++)
#pragma unroll
            for (int r = 0; r < 4; r++) {
                int srow = wr * 64 + rt * 16 + q * 4 + r;
                int mc = cc * 64 + wc * 32 + ct * 16 + l15;
                Y[(long)(m * 128 + srow) * DIM + mc] = __float2bfloat16(acc[rt][ct][r]);
            }
}

// ---------------------------------------------------------------------------
// Final gather-combine: out[t] = Ys[t] + Ye[offs[e1]+s1] + Ye[offs[e2]+s2].
// ---------------------------------------------------------------------------
__global__ __launch_bounds__(256) void combine_kernel(const bf16* __restrict__ Ys,
                                                      const bf16* __restrict__ Ye,
                                                      const int2* __restrict__ te,
                                                      const int* __restrict__ s1a,
                                                      const int* __restrict__ s2a,
                                                      const int* __restrict__ offs,
                                                      float* __restrict__ out) {
    int idx = blockIdx.x * 256 + threadIdx.x;   // NTOK*DIM/8 total
    int t = idx >> 7;
    int d = (idx & 127) * 8;
    int2 ee = te[t];
    long r1 = (long)(offs[ee.x] + s1a[t]);
    long r2 = (long)(offs[ee.y] + s2a[t]);
    bf16x8 a = *(const bf16x8*)(Ys + (long)t * DIM + d);
    bf16x8 p = *(const bf16x8*)(Ye + r1 * DIM + d);
    bf16x8 r = *(const bf16x8*)(Ye + r2 * DIM + d);
    float* o = out + (long)t * DIM + d;
#pragma unroll
    for (int i = 0; i < 8; i++)
        o[i] = b2f(a[i]) + b2f(p[i]) + b2f(r[i]);
}

// ---------------------------------------------------------------------------
extern "C" void kernel_launch(void* const* d_in, const int* in_sizes, int n_in,
                              void* d_out, int out_size, void* d_ws, size_t ws_size,
                              hipStream_t stream) {
    const float* x    = (const float*)d_in[0];
    const float* W_g  = (const float*)d_in[1];
    const float* Wg_e = (const float*)d_in[2];
    const float* Wu_e = (const float*)d_in[3];
    const float* Wd_e = (const float*)d_in[4];
    const float* Wg_s = (const float*)d_in[5];
    const float* Wu_s = (const float*)d_in[6];
    const float* Wd_s = (const float*)d_in[7];
    float* out = (float*)d_out;

    bf16* Xb = (bf16*)d_ws;                            // [2048,1024]
    bf16* Bg = Xb + (size_t)NTOK * DIM;                // [5120,1024]
    bf16* Bu = Bg + (size_t)KH * DIM;                  // [5120,1024]
    bf16* Bd = Bu + (size_t)KH * DIM;                  // [1024,5120]
    bf16* Hs = Bd + (size_t)DIM * KH;                  // [2048,1024]
    bf16* He = Hs + (size_t)NTOK * DSH;                // [5120,512] compacted
    bf16* Ys = He + (size_t)MAXROWS * DEXP;            // [2048,1024]
    bf16* Ye = Ys + (size_t)NTOK * DIM;                // [5120,1024] compacted
    int*  counts   = (int*)(Ye + (size_t)MAXROWS * DIM);
    int*  offs     = counts + NEXP;
    int*  tok_list = offs + NEXP;                      // [8,2048]
    float* cw      = (float*)(tok_list + NEXP * NTOK); // [8,2048]
    int*  s1a      = (int*)(cw + NEXP * NTOK);         // [2048]
    int*  s2a      = s1a + NTOK;                       // [2048]
    int2* te       = (int2*)(s2a + NTOK);              // [2048]
    float2* tp     = (float2*)(te + NTOK);             // [2048]

    pack_gate<<<PACKBLOCKS + NTOK / 2, 128, 0, stream>>>(
        Wg_s, Wu_s, Wg_e, Wu_e, x, W_g, Bg, Bu, Xb, te, tp);
    assign_kernel<<<1, 512, 0, stream>>>(te, tp, counts, offs, tok_list, cw, s1a, s2a);
    gu_all<<<2560, 256, 0, stream>>>(Xb, Bg, Bu, counts, offs, tok_list, cw,
                                     Wd_s, Wd_e, Bd, Hs, He);
    down_all<<<2304, 256, 0, stream>>>(Hs, He, Bd, counts, offs, Ys, Ye);
    combine_kernel<<<NTOK * DIM / 8 / 256, 256, 0, stream>>>(Ys, Ye, te, s1a, s2a, offs, out);
}

// Round 9
// 199.007 us; speedup vs baseline: 1.3141x; 1.0121x over previous
//
#include <hip/hip_runtime.h>
#include <hip/hip_bf16.h>

#define NTOK 2048
#define DIM  1024
#define DEXP 512
#define NEXP 8
#define DSH  1024          // shared expert width
#define KH   5120          // DSH + NEXP*DEXP (packed Bg/Bu row count; Bd col count)
#define MAXROWS 5120       // compacted routed slots upper bound
#define PACKBLOCKS 2560    // Bg+Bu tiles only (Bd pack folded into gu_all)

typedef __hip_bfloat16 bf16;
typedef __attribute__((ext_vector_type(8))) short bf16x8;
typedef __attribute__((ext_vector_type(4))) float floatx4;

// async global->LDS, 16B/lane. LDS dest = wave-uniform base + lane*16 (HW adds).
__device__ __forceinline__ void gl_lds16(const bf16* g, bf16* l) {
    __builtin_amdgcn_global_load_lds(
        (const __attribute__((address_space(1))) void*)g,
        (__attribute__((address_space(3))) void*)l, 16, 0, 0);
}

__device__ __forceinline__ float b2f(short s) {
    union { float f; unsigned u; } v;
    v.u = ((unsigned)(unsigned short)s) << 16;
    return v.f;
}

struct B4 { bf16 a, b, c, d; };   // 8-byte bf16 quad

// ---------------------------------------------------------------------------
// Fused Bg/Bu-pack + gating kernel (128 threads/block). R2-proven LDS pack.
// ---------------------------------------------------------------------------
__global__ __launch_bounds__(128) void pack_gate(
        const float* __restrict__ Wg_s, const float* __restrict__ Wu_s,
        const float* __restrict__ Wg_e, const float* __restrict__ Wu_e,
        const float* __restrict__ x, const float* __restrict__ Wg,
        bf16* __restrict__ Bg, bf16* __restrict__ Bu,
        bf16* __restrict__ Xb, int2* __restrict__ te, float2* __restrict__ tp) {
    int b = blockIdx.x;
    const int tid = threadIdx.x;
    if (b < PACKBLOCKS) {
        // ---- pack: src [R][C] fp32, dst[h = src col][k = src row] bf16 ----
        __shared__ unsigned lt[64][35];
        const float* src; bf16* dst; int C; long dstBase; int tilesX;
        if (b < 256)        { src = Wg_s; dst = Bg; C = 1024; dstBase = 0; tilesX = 16; }
        else if (b < 1280)  { int z = (b - 256) >> 7; b = (b - 256) & 127;
                              src = Wg_e + (long)z * DIM * DEXP; dst = Bg; C = 512;
                              dstBase = (long)(DSH + z * DEXP) * 1024; tilesX = 8; }
        else if (b < 1536)  { b -= 1280; src = Wu_s; dst = Bu; C = 1024; dstBase = 0; tilesX = 16; }
        else                { int z = (b - 1536) >> 7; b = (b - 1536) & 127;
                              src = Wu_e + (long)z * DIM * DEXP; dst = Bu; C = 512;
                              dstBase = (long)(DSH + z * DEXP) * 1024; tilesX = 8; }
        const int tileX = b & (tilesX - 1), tileY = b / tilesX;
        const int c0 = tileX * 64, r0 = tileY * 64;

        // load 64x64 fp32, 8 independent float4/lane, cvt->bf16, pack to LDS
        const int lrow = tid >> 4, lch = tid & 15;
#pragma unroll
        for (int i = 0; i < 8; i++) {
            int row = lrow + i * 8;
            float4 v = *(const float4*)(src + (long)(r0 + row) * C + c0 + lch * 4);
            union { bf16 h[2]; unsigned u; } p0, p1;
            p0.h[0] = __float2bfloat16(v.x); p0.h[1] = __float2bfloat16(v.y);
            p1.h[0] = __float2bfloat16(v.z); p1.h[1] = __float2bfloat16(v.w);
            lt[row][lch * 2]     = p0.u;
            lt[row][lch * 2 + 1] = p1.u;
        }
        __syncthreads();
        // transposed store: each lane emits one 16B bf16x8 (8 k of one h)
        const int kc = tid & 7;
#pragma unroll
        for (int i = 0; i < 4; i++) {
            int h = (tid >> 3) + i * 16;
            union { unsigned short s[8]; bf16x8 v8; } o;
#pragma unroll
            for (int j = 0; j < 8; j++)
                o.s[j] = ((const unsigned short*)lt[kc * 8 + j])[h];
            *(bf16x8*)(dst + dstBase + (long)(c0 + h) * 1024 + r0 + kc * 8) = o.v8;
        }
    } else {
        // ---- gating: one wave/token, fp32 logits -> softmax -> top-2 ----
        int t = (b - PACKBLOCKS) * 2 + (tid >> 6);
        int lane = tid & 63;
        const float* xr = x + (long)t * DIM;
        bf16* xo = Xb + (long)t * DIM;
        float acc[NEXP] = {0.f, 0.f, 0.f, 0.f, 0.f, 0.f, 0.f, 0.f};
#pragma unroll
        for (int i = 0; i < 4; i++) {
            int d = lane * 4 + i * 256;
            float4 xv = *(const float4*)(xr + d);
            B4 o{__float2bfloat16(xv.x), __float2bfloat16(xv.y),
                 __float2bfloat16(xv.z), __float2bfloat16(xv.w)};
            *(B4*)(xo + d) = o;
#pragma unroll
            for (int j = 0; j < 4; j++) {
                float xs = (j == 0) ? xv.x : (j == 1) ? xv.y : (j == 2) ? xv.z : xv.w;
                float4 w0 = *(const float4*)(Wg + (d + j) * NEXP);
                float4 w1 = *(const float4*)(Wg + (d + j) * NEXP + 4);
                acc[0] += xs * w0.x; acc[1] += xs * w0.y; acc[2] += xs * w0.z; acc[3] += xs * w0.w;
                acc[4] += xs * w1.x; acc[5] += xs * w1.y; acc[6] += xs * w1.z; acc[7] += xs * w1.w;
            }
        }
#pragma unroll
        for (int e = 0; e < NEXP; e++)
#pragma unroll
            for (int off = 32; off; off >>= 1)
                acc[e] += __shfl_xor(acc[e], off);
        if (lane == 0) {
            float m = acc[0];
#pragma unroll
            for (int e = 1; e < NEXP; e++) m = fmaxf(m, acc[e]);
            float p[NEXP], s = 0.f;
#pragma unroll
            for (int e = 0; e < NEXP; e++) { p[e] = expf(acc[e] - m); s += p[e]; }
            float inv = 1.f / s;
#pragma unroll
            for (int e = 0; e < NEXP; e++) p[e] *= inv;
            int i1 = 0;
#pragma unroll
            for (int e = 1; e < NEXP; e++) if (p[e] > p[i1]) i1 = e;   // strict >: lowest idx on tie
            int i2 = (i1 == 0) ? 1 : 0;
#pragma unroll
            for (int e = 0; e < NEXP; e++) if (e != i1 && p[e] > p[i2]) i2 = e;
            te[t] = make_int2(i1, i2);
            tp[t] = make_float2(p[i1], p[i2]);
        }
    }
}

// ---------------------------------------------------------------------------
// Phase-2 slot assignment: 1 block, 8 waves; ballot prefix -> deterministic
// slots. Zero atomics. Zeroes pad slots (token 0, weight 0).
// ---------------------------------------------------------------------------
__global__ __launch_bounds__(512) void assign_kernel(const int2* __restrict__ te,
                                                     const float2* __restrict__ tp,
                                                     int* __restrict__ counts,
                                                     int* __restrict__ offs,
                                                     int* __restrict__ tok_list,
                                                     float* __restrict__ cw,
                                                     int* __restrict__ s1a,
                                                     int* __restrict__ s2a) {
    __shared__ int cnt[NEXP];
    const int e = threadIdx.x >> 6;
    const int lane = threadIdx.x & 63;
    int base = 0;
    for (int t0 = 0; t0 < NTOK; t0 += 64) {
        int t = t0 + lane;
        int2 ee = te[t];
        bool m1 = (ee.x == e), m2 = (ee.y == e);
        bool mt = m1 || m2;
        unsigned long long mask = __ballot(mt);
        int pre = __popcll(mask & ((1ull << lane) - 1ull));
        if (mt) {
            int slot = base + pre;
            tok_list[e * NTOK + slot] = t;
            float2 pp = tp[t];
            cw[e * NTOK + slot] = m1 ? pp.x : pp.y;
            if (m1) s1a[t] = slot; else s2a[t] = slot;
        }
        base += __popcll(mask);
    }
    // zero pad slots up to the 128-rounded count (read as token 0 / weight 0)
    int rounded = (base + 127) & ~127;
    for (int s = base + lane; s < rounded; s += 64) {
        tok_list[e * NTOK + s] = 0;
        cw[e * NTOK + s] = 0.f;
    }
    if (lane == 0) cnt[e] = base;
    __syncthreads();
    if (threadIdx.x == 0) {
        int o = 0;
#pragma unroll
        for (int i = 0; i < NEXP; i++) {
            counts[i] = cnt[i];
            offs[i] = o;
            o += (cnt[i] + 127) & ~127;
        }
    }
}

// ---------------------------------------------------------------------------
// Unified gate+up SwiGLU GEMM + Bd-pack backfill (R8-proven, 201.4us total).
// ---------------------------------------------------------------------------
__global__ __launch_bounds__(256) void gu_all(const bf16* __restrict__ X,
                                              const bf16* __restrict__ Bg,
                                              const bf16* __restrict__ Bu,
                                              const int* __restrict__ counts,
                                              const int* __restrict__ offs,
                                              const int* __restrict__ tok_list,
                                              const float* __restrict__ cw,
                                              const float* __restrict__ Wd_s,
                                              const float* __restrict__ Wd_e,
                                              bf16* __restrict__ Bd,
                                              bf16* __restrict__ Hs,
                                              bf16* __restrict__ He) {
    __shared__ __align__(16) bf16 sA[3][128 * 32];
    __shared__ __align__(16) bf16 sBg[3][64 * 32];
    __shared__ __align__(16) bf16 sBu[3][64 * 32];

    const int b = blockIdx.x;

    if (b >= 1280) {
        // ---- Bd pack tile (256 threads), LDS scratch aliases sA ----
        unsigned* lt = (unsigned*)&sA[0][0];           // [64][35] dwords
        int pb = b - 1280;
        const float* src; long dstBase; int tileX, tileY;
        if (pb < 256) {                                // Wd_s [1024][1024] -> Bd[d][k]
            src = Wd_s; dstBase = 0;
            tileX = pb & 15; tileY = pb >> 4;          // 16x16 tiles
        } else {                                       // Wd_e[z] [512][1024] -> Bd[d][DSH+z*512+k]
            int q = pb - 256; int z = q >> 7; q &= 127;
            src = Wd_e + (long)z * DEXP * DIM;
            dstBase = DSH + (long)z * DEXP;
            tileX = q & 15; tileY = q >> 4;            // 8 rows x 16 cols of tiles
        }
        const int c0 = tileX * 64, r0 = tileY * 64;    // c0: src col (d), r0: src row (k)
        const int tid = threadIdx.x;
        const int lrow = tid >> 4, lch = tid & 15;     // 16 rows x 16 f4-chunks
#pragma unroll
        for (int i = 0; i < 4; i++) {
            int row = lrow + i * 16;
            float4 v = *(const float4*)(src + (long)(r0 + row) * DIM + c0 + lch * 4);
            union { bf16 h[2]; unsigned u; } p0, p1;
            p0.h[0] = __float2bfloat16(v.x); p0.h[1] = __float2bfloat16(v.y);
            p1.h[0] = __float2bfloat16(v.z); p1.h[1] = __float2bfloat16(v.w);
            lt[row * 35 + lch * 2]     = p0.u;
            lt[row * 35 + lch * 2 + 1] = p1.u;
        }
        __syncthreads();
        const int kc = tid & 7;
#pragma unroll
        for (int i = 0; i < 2; i++) {
            int h = (tid >> 3) + i * 32;               // dst row (src col d)
            union { unsigned short s[8]; bf16x8 v8; } o;
#pragma unroll
            for (int j = 0; j < 8; j++)
                o.s[j] = ((const unsigned short*)(lt + (kc * 8 + j) * 35))[h];
            *(bf16x8*)(Bd + (long)(c0 + h) * KH + dstBase + r0 + kc * 8) = o.v8;
        }
        return;
    }

    const bool routed = b < 1024;
    int e = 0, m, c;
    if (routed) {
        e = b >> 7; m = (b >> 3) & 15; c = b & 7;
        if (m * 128 >= counts[e]) return;
    } else {
        int bs = b - 1024; m = bs >> 4; c = bs & 15;
    }
    const int so = routed ? offs[e] : 0;               // compacted slot base
    const int colB0 = routed ? (DSH + e * DEXP + c * 64) : c * 64;

    const int tid = threadIdx.x;
    const int wave = tid >> 6, lane = tid & 63;
    const int wr = wave >> 1, wc = wave & 1;
    const int q = lane >> 4, l15 = lane & 15;
    const int koff = (q ^ ((l15 >> 1) & 3)) * 8;       // swizzled fragment read

    const int r0 = tid >> 2, c4 = tid & 3;
    const int r1 = r0 + 64;
    const int c4s = c4 ^ ((r0 >> 1) & 3);
    long aRow0, aRow1;
    if (routed) {
        const int* tl = tok_list + e * NTOK + m * 128;
        aRow0 = (long)tl[r0] * DIM;
        aRow1 = (long)tl[r1] * DIM;
    } else {
        aRow0 = (long)(m * 128 + r0) * DIM;
        aRow1 = (long)(m * 128 + r1) * DIM;
    }
    const long bRow = (long)(colB0 + r0) * DIM;

    floatx4 accG[4][2], accU[4][2];
    const floatx4 z4 = {0.f, 0.f, 0.f, 0.f};
#pragma unroll
    for (int i = 0; i < 4; i++)
#pragma unroll
        for (int j = 0; j < 2; j++) { accG[i][j] = z4; accU[i][j] = z4; }

    auto stage = [&](int bb, int k0) {
        gl_lds16(X + aRow0 + k0 + c4s * 8, &sA[bb][wave * 512]);
        gl_lds16(X + aRow1 + k0 + c4s * 8, &sA[bb][2048 + wave * 512]);
        gl_lds16(Bg + bRow + k0 + c4s * 8, &sBg[bb][wave * 512]);
        gl_lds16(Bu + bRow + k0 + c4s * 8, &sBu[bb][wave * 512]);
    };
    auto compute = [&](int bb) {
        bf16x8 af[4], bgv[2], buv[2];
#pragma unroll
        for (int rt = 0; rt < 4; rt++)
            af[rt] = *(const bf16x8*)(&sA[bb][(wr * 64 + rt * 16 + l15) * 32 + koff]);
#pragma unroll
        for (int ct = 0; ct < 2; ct++) {
            int cb = (wc * 32 + ct * 16 + l15) * 32 + koff;
            bgv[ct] = *(const bf16x8*)(&sBg[bb][cb]);
            buv[ct] = *(const bf16x8*)(&sBu[bb][cb]);
        }
#pragma unroll
        for (int rt = 0; rt < 4; rt++)
#pragma unroll
            for (int ct = 0; ct < 2; ct++) {
                accG[rt][ct] = __builtin_amdgcn_mfma_f32_16x16x32_bf16(af[rt], bgv[ct], accG[rt][ct], 0, 0, 0);
                accU[rt][ct] = __builtin_amdgcn_mfma_f32_16x16x32_bf16(af[rt], buv[ct], accU[rt][ct], 0, 0, 0);
            }
    };

    const int NS = DIM / 32;               // 32 K-steps
    stage(0, 0);
    stage(1, 32);                          // 2 stages in flight
    int bb = 0;
    for (int ks = 0; ks < NS; ks++) {
        if (ks + 2 < NS) stage((bb + 2) % 3, (ks + 2) * 32);
        if (ks + 2 < NS)      asm volatile("s_waitcnt vmcnt(8)" ::: "memory");
        else if (ks + 1 < NS) asm volatile("s_waitcnt vmcnt(4)" ::: "memory");
        else                  asm volatile("s_waitcnt vmcnt(0)" ::: "memory");
        __builtin_amdgcn_s_barrier();      // raw: no compiler vmcnt(0) drain
        asm volatile("" ::: "memory");
        compute(bb);
        asm volatile("" ::: "memory");
        __builtin_amdgcn_s_barrier();      // protect buffer bb from next stage
        bb = (bb + 1) % 3;
    }

    // epilogue: silu(g)*u*w  (C/D layout: col=lane&15, row=q*4+reg)
    float wv[4][4];
#pragma unroll
    for (int rt = 0; rt < 4; rt++)
#pragma unroll
        for (int r = 0; r < 4; r++) {
            int srow = wr * 64 + rt * 16 + q * 4 + r;
            wv[rt][r] = routed ? cw[e * NTOK + m * 128 + srow] : 1.0f;
        }
#pragma unroll
    for (int rt = 0; rt < 4; rt++)
#pragma unroll
        for (int ct = 0; ct < 2; ct++)
#pragma unroll
            for (int r = 0; r < 4; r++) {
                int srow = wr * 64 + rt * 16 + q * 4 + r;
                int colLoc = c * 64 + wc * 32 + ct * 16 + l15;
                float g = accG[rt][ct][r];
                float u = accU[rt][ct][r];
                float h = (g / (1.f + __expf(-g))) * u * wv[rt][r];
                if (routed)
                    He[(long)(so + m * 128 + srow) * DEXP + colLoc] = __float2bfloat16(h);
                else
                    Hs[(long)(m * 128 + srow) * DSH + colLoc] = __float2bfloat16(h);
            }
}

// ---------------------------------------------------------------------------
// Unified down GEMM, NO atomics. NEW: split-K for the shared expert — the
// 256 shared blocks (32 phases) were the dispatch tail; now 512 blocks x 16
// phases writing two bf16 partials (Ys = K-half 0, Ys2 = K-half 1). Every
// block now runs exactly 16 phases. combine sums 4 terms.
// ---------------------------------------------------------------------------
__global__ __launch_bounds__(256) void down_all(const bf16* __restrict__ Hs,
                                                const bf16* __restrict__ He,
                                                const bf16* __restrict__ Bd,
                                                const int* __restrict__ counts,
                                                const int* __restrict__ offs,
                                                bf16* __restrict__ Ys,
                                                bf16* __restrict__ Ys2,
                                                bf16* __restrict__ Ye) {
    __shared__ __align__(16) bf16 sA[3][128 * 32];
    __shared__ __align__(16) bf16 sB[3][64 * 32];

    const int b = blockIdx.x;
    const bool routed = b < 2048;
    int e = 0, m, cc, kh = 0;
    if (routed) {
        e = b >> 8; m = (b >> 4) & 15; cc = b & 15;
        if (m * 128 >= counts[e]) return;
    } else {
        int bs = b - 2048;                 // 0..511: shared split-K
        kh = bs & 1;                       // K-half
        int r = bs >> 1;                   // 0..255
        m = r >> 4; cc = r & 15;
    }
    const int so = routed ? offs[e] : 0;
    const bf16* A = routed ? He + (long)so * DEXP : Hs;
    bf16* Y = routed ? Ye + (long)so * DIM : (kh ? Ys2 : Ys);
    const int astr = routed ? DEXP : DSH;
    const int aOffK = routed ? 0 : kh * 512;           // K-offset within A row
    const int ksteps = 16;                             // uniform: 512/32 for all
    const int kg0 = routed ? (DSH + e * DEXP) : kh * 512;  // K-offset in Bd cols

    const int tid = threadIdx.x;
    const int wave = tid >> 6, lane = tid & 63;
    const int wr = wave >> 1, wc = wave & 1;
    const int q = lane >> 4, l15 = lane & 15;
    const int koff = (q ^ ((l15 >> 1) & 3)) * 8;

    const int r0 = tid >> 2, c4 = tid & 3;
    const int r1 = r0 + 64;
    const int c4s = c4 ^ ((r0 >> 1) & 3);
    const long aRow0 = (long)(m * 128 + r0) * astr + aOffK;
    const long aRow1 = (long)(m * 128 + r1) * astr + aOffK;
    const long bRow = (long)(cc * 64 + r0) * KH + kg0;

    floatx4 acc[4][2];
    const floatx4 z4 = {0.f, 0.f, 0.f, 0.f};
#pragma unroll
    for (int i = 0; i < 4; i++)
#pragma unroll
        for (int j = 0; j < 2; j++) acc[i][j] = z4;

    auto stage = [&](int bb, int k0) {
        gl_lds16(A + aRow0 + k0 + c4s * 8, &sA[bb][wave * 512]);
        gl_lds16(A + aRow1 + k0 + c4s * 8, &sA[bb][2048 + wave * 512]);
        gl_lds16(Bd + bRow + k0 + c4s * 8, &sB[bb][wave * 512]);
    };
    auto compute = [&](int bb) {
        bf16x8 af[4], bb2[2];
#pragma unroll
        for (int rt = 0; rt < 4; rt++)
            af[rt] = *(const bf16x8*)(&sA[bb][(wr * 64 + rt * 16 + l15) * 32 + koff]);
#pragma unroll
        for (int ct = 0; ct < 2; ct++)
            bb2[ct] = *(const bf16x8*)(&sB[bb][(wc * 32 + ct * 16 + l15) * 32 + koff]);
#pragma unroll
        for (int rt = 0; rt < 4; rt++)
#pragma unroll
            for (int ct = 0; ct < 2; ct++)
                acc[rt][ct] = __builtin_amdgcn_mfma_f32_16x16x32_bf16(af[rt], bb2[ct], acc[rt][ct], 0, 0, 0);
    };

    stage(0, 0);
    stage(1, 32);                          // 2 stages in flight
    int bb = 0;
    for (int ks = 0; ks < ksteps; ks++) {
        if (ks + 2 < ksteps) stage((bb + 2) % 3, (ks + 2) * 32);
        if (ks + 2 < ksteps)      asm volatile("s_waitcnt vmcnt(6)" ::: "memory");
        else if (ks + 1 < ksteps) asm volatile("s_waitcnt vmcnt(3)" ::: "memory");
        else                      asm volatile("s_waitcnt vmcnt(0)" ::: "memory");
        __builtin_amdgcn_s_barrier();
        asm volatile("" ::: "memory");
        compute(bb);
        asm volatile("" ::: "memory");
        __builtin_amdgcn_s_barrier();
        bb = (bb + 1) % 3;
    }

#pragma unroll
    for (int rt = 0; rt < 4; rt++)
#pragma unroll
        for (int ct = 0; ct < 2; ct++)
#pragma unroll
            for (int r = 0; r < 4; r++) {
                int srow = wr * 64 + rt * 16 + q * 4 + r;
                int mc = cc * 64 + wc * 32 + ct * 16 + l15;
                Y[(long)(m * 128 + srow) * DIM + mc] = __float2bfloat16(acc[rt][ct][r]);
            }
}

// ---------------------------------------------------------------------------
// Final gather-combine: out[t] = Ys[t] + Ys2[t] + Ye[offs[e1]+s1] + Ye[offs[e2]+s2].
// ---------------------------------------------------------------------------
__global__ __launch_bounds__(256) void combine_kernel(const bf16* __restrict__ Ys,
                                                      const bf16* __restrict__ Ys2,
                                                      const bf16* __restrict__ Ye,
                                                      const int2* __restrict__ te,
                                                      const int* __restrict__ s1a,
                                                      const int* __restrict__ s2a,
                                                      const int* __restrict__ offs,
                                                      float* __restrict__ out) {
    int idx = blockIdx.x * 256 + threadIdx.x;   // NTOK*DIM/8 total
    int t = idx >> 7;
    int d = (idx & 127) * 8;
    int2 ee = te[t];
    long r1 = (long)(offs[ee.x] + s1a[t]);
    long r2 = (long)(offs[ee.y] + s2a[t]);
    bf16x8 a = *(const bf16x8*)(Ys + (long)t * DIM + d);
    bf16x8 a2 = *(const bf16x8*)(Ys2 + (long)t * DIM + d);
    bf16x8 p = *(const bf16x8*)(Ye + r1 * DIM + d);
    bf16x8 r = *(const bf16x8*)(Ye + r2 * DIM + d);
    float* o = out + (long)t * DIM + d;
#pragma unroll
    for (int i = 0; i < 8; i++)
        o[i] = b2f(a[i]) + b2f(a2[i]) + b2f(p[i]) + b2f(r[i]);
}

// ---------------------------------------------------------------------------
extern "C" void kernel_launch(void* const* d_in, const int* in_sizes, int n_in,
                              void* d_out, int out_size, void* d_ws, size_t ws_size,
                              hipStream_t stream) {
    const float* x    = (const float*)d_in[0];
    const float* W_g  = (const float*)d_in[1];
    const float* Wg_e = (const float*)d_in[2];
    const float* Wu_e = (const float*)d_in[3];
    const float* Wd_e = (const float*)d_in[4];
    const float* Wg_s = (const float*)d_in[5];
    const float* Wu_s = (const float*)d_in[6];
    const float* Wd_s = (const float*)d_in[7];
    float* out = (float*)d_out;

    bf16* Xb = (bf16*)d_ws;                            // [2048,1024]
    bf16* Bg = Xb + (size_t)NTOK * DIM;                // [5120,1024]
    bf16* Bu = Bg + (size_t)KH * DIM;                  // [5120,1024]
    bf16* Bd = Bu + (size_t)KH * DIM;                  // [1024,5120]
    bf16* Hs = Bd + (size_t)DIM * KH;                  // [2048,1024]
    bf16* He = Hs + (size_t)NTOK * DSH;                // [5120,512] compacted
    bf16* Ys = He + (size_t)MAXROWS * DEXP;            // [2048,1024] shared K-half 0
    bf16* Ys2 = Ys + (size_t)NTOK * DIM;               // [2048,1024] shared K-half 1
    bf16* Ye = Ys2 + (size_t)NTOK * DIM;               // [5120,1024] compacted
    int*  counts   = (int*)(Ye + (size_t)MAXROWS * DIM);
    int*  offs     = counts + NEXP;
    int*  tok_list = offs + NEXP;                      // [8,2048]
    float* cw      = (float*)(tok_list + NEXP * NTOK); // [8,2048]
    int*  s1a      = (int*)(cw + NEXP * NTOK);         // [2048]
    int*  s2a      = s1a + NTOK;                       // [2048]
    int2* te       = (int2*)(s2a + NTOK);              // [2048]
    float2* tp     = (float2*)(te + NTOK);             // [2048]

    pack_gate<<<PACKBLOCKS + NTOK / 2, 128, 0, stream>>>(
        Wg_s, Wu_s, Wg_e, Wu_e, x, W_g, Bg, Bu, Xb, te, tp);
    assign_kernel<<<1, 512, 0, stream>>>(te, tp, counts, offs, tok_list, cw, s1a, s2a);
    gu_all<<<2560, 256, 0, stream>>>(Xb, Bg, Bu, counts, offs, tok_list, cw,
                                     Wd_s, Wd_e, Bd, Hs, He);
    down_all<<<2560, 256, 0, stream>>>(Hs, He, Bd, counts, offs, Ys, Ys2, Ye);
    combine_kernel<<<NTOK * DIM / 8 / 256, 256, 0, stream>>>(Ys, Ys2, Ye, te, s1a, s2a, offs, out);
}